// Round 10
// baseline (71.690 us; speedup 1.0000x reference)
//
#include <hip/hip_runtime.h>
#include <cstddef>
#include <cstdint>

#define Bq 64
#define Tq 90
#define Oq 5
#define Dq 256
#define Hq 256
#define EAq 4096
#define Rq 5
#define NBq 8
#define NPGq 95
#define Nq 6080           // B*NPG real nodes
#define NPq 6144          // padded node space: 64 graphs x 96
#define EPBq 4546         // EA + T*O
#define Eq 290944         // B*EPB
#define KKq 1536          // (R+1)*D rows of WT / xwT
#define KAq 480           // A2 cols: 5 relations x 96

typedef __attribute__((ext_vector_type(8))) short bf16x8;
typedef __attribute__((ext_vector_type(8))) unsigned short u16x8;
typedef __attribute__((ext_vector_type(4))) float f32x4;
typedef __attribute__((address_space(1))) const unsigned int gu32;
typedef __attribute__((address_space(3))) unsigned int lu32;

__device__ __forceinline__ unsigned short f2bf(float f) {
    unsigned u = __float_as_uint(f);
    unsigned r = (u + 0x7FFF + ((u >> 16) & 1)) >> 16;
    return (unsigned short)r;
}
__device__ __forceinline__ float bf2f(unsigned short s) {
    return __uint_as_float(((unsigned)s) << 16);
}

// ---------------- fused prep:
// blocks 0..2879: zero A2f; 2880..3647: x->xb bf16; 3648..3695: Wt compute
__global__ __launch_bounds__(256) void k_prep(const float* __restrict__ x,
                                              const float* __restrict__ bases,
                                              const float* __restrict__ comp,
                                              const float* __restrict__ rootw,
                                              unsigned short* __restrict__ xb,
                                              unsigned short* __restrict__ Wt,
                                              float* __restrict__ A2f) {
    __shared__ float Ld[32][257];
    int blk = blockIdx.x;
    if (blk < 2880) {
        unsigned i = blk * 256 + threadIdx.x;       // 737280 float4s == 11,796,480 B
        ((float4*)A2f)[i] = make_float4(0.f, 0.f, 0.f, 0.f);
        return;
    }
    if (blk < 3648) {
        unsigned i = (blk - 2880) * 256 + threadIdx.x;  // over NPq*32 chunks of 8
        unsigned np = i >> 5, c = i & 31;
        unsigned s = np % 96;
        u16x8 pk;
        if (s == 95) {
#pragma unroll
            for (int q = 0; q < 8; ++q) pk[q] = 0;
        } else {
            unsigned node = np - np / 96;
            const float4* xs = (const float4*)(x + (size_t)node * Dq + c * 8);
            float4 a = xs[0], b2 = xs[1];
            pk[0] = f2bf(a.x);  pk[1] = f2bf(a.y);  pk[2] = f2bf(a.z);  pk[3] = f2bf(a.w);
            pk[4] = f2bf(b2.x); pk[5] = f2bf(b2.y); pk[6] = f2bf(b2.z); pk[7] = f2bf(b2.w);
        }
        *(u16x8*)(xb + (size_t)np * Dq + c * 8) = pk;
        return;
    }
    // Wt: WT[kk][d] bf16; kk=r*256+h or 1280+h (root)
    int wblk = blk - 3648;            // 0..47
    int rs = wblk >> 3;               // 0..5
    int d0 = (wblk & 7) * 32;
    int t = threadIdx.x;              // h
    float cmp[NBq];
    if (rs < Rq)
#pragma unroll
        for (int nb = 0; nb < NBq; ++nb) cmp[nb] = comp[rs * NBq + nb];
    for (int dl = 0; dl < 32; ++dl) {
        int d = d0 + dl;
        float v;
        if (rs < Rq) {
            v = 0.f;
#pragma unroll
            for (int nb = 0; nb < NBq; ++nb)
                v += cmp[nb] * bases[((size_t)nb * Dq + d) * Hq + t];
        } else {
            v = rootw[(size_t)d * Hq + t];
        }
        Ld[dl][t] = v;
    }
    __syncthreads();
    int c = t & 31, hg = t >> 5;
    for (int hh = 0; hh < 32; ++hh) {
        int h = hg * 32 + hh;
        Wt[(size_t)(rs * 256 + h) * Dq + d0 + c] = f2bf(Ld[c][h]);
    }
}

// ---------------- attn, s-split: block (b, half) computes PT[48 s][96 t] = Ws_half @ M_b^T,
//                  row-local softmax (8-lane groups), scatters its half's edges into A2f[b]
__global__ __launch_bounds__(576) void k_attn(const float* __restrict__ M,
                                              const float* __restrict__ Ws,
                                              const float* __restrict__ natt,
                                              const int* __restrict__ esrc,
                                              const int* __restrict__ edst,
                                              const int* __restrict__ etype,
                                              float* __restrict__ A2f) {
    __shared__ __attribute__((aligned(16))) char lds[74112];
    unsigned short* Mb  = (unsigned short*)lds;           // [96][256] bf16 swizzled (48KB)
    unsigned short* Wsb = (unsigned short*)(lds + 49152); // [48][256] bf16 swizzled (24KB)
    float* P   = (float*)lds;                             // [48][97] fp32 (reuses Mb region)
    float* mxs = (float*)(lds + 73728);                   // [48]
    float* rds = (float*)(lds + 73920);                   // [48]
    const int blk = blockIdx.x;
    const int b = blk >> 1, s0 = (blk & 1) * 48;
    const int tid = threadIdx.x;

#pragma unroll
    for (int i = 0; i < 8; ++i) {
        int idx = tid + i * 576;            // 0..4607
        if (idx < 3072) {
            int row = idx >> 5, c = idx & 31;
            u16x8 pm;
            if (row < Tq) {
                const float4* ms = (const float4*)(M + ((size_t)b * Tq + row) * Dq + c * 8);
                float4 a0 = ms[0], a1 = ms[1];
                pm[0] = f2bf(a0.x); pm[1] = f2bf(a0.y); pm[2] = f2bf(a0.z); pm[3] = f2bf(a0.w);
                pm[4] = f2bf(a1.x); pm[5] = f2bf(a1.y); pm[6] = f2bf(a1.z); pm[7] = f2bf(a1.w);
            } else {
#pragma unroll
                for (int q = 0; q < 8; ++q) pm[q] = 0;
            }
            int off = row * 512 + ((c * 16) ^ ((row & 7) << 4));
            *(u16x8*)((char*)Mb + off) = pm;
        } else {
            int k = idx - 3072;
            int lrow = k >> 5, c = k & 31;
            int grow = s0 + lrow;
            u16x8 pw;
            if (grow < Tq) {
                const float4* ws = (const float4*)(Ws + (size_t)grow * Dq + c * 8);
                float4 w0 = ws[0], w1 = ws[1];
                pw[0] = f2bf(w0.x); pw[1] = f2bf(w0.y); pw[2] = f2bf(w0.z); pw[3] = f2bf(w0.w);
                pw[4] = f2bf(w1.x); pw[5] = f2bf(w1.y); pw[6] = f2bf(w1.z); pw[7] = f2bf(w1.w);
            } else {
#pragma unroll
                for (int q = 0; q < 8; ++q) pw[q] = 0;
            }
            int off = lrow * 512 + ((c * 16) ^ ((lrow & 7) << 4));
            *(u16x8*)((char*)Wsb + off) = pw;
        }
    }
    __syncthreads();

    const int w = tid >> 6, l = tid & 63;
    const int wr = w / 3, wc = w % 3;
    f32x4 acc[2];
    acc[0] = (f32x4)0.0f;
    acc[1] = (f32x4)0.0f;
#pragma unroll
    for (int ks = 0; ks < 8; ++ks) {
        int kb = ks * 64 + (l >> 4) * 16;
        int srow = wr * 16 + (l & 15);
        bf16x8 af = *(const bf16x8*)((char*)Wsb + srow * 512 + (kb ^ ((srow & 7) << 4)));
#pragma unroll
        for (int ni = 0; ni < 2; ++ni) {
            int trow = wc * 32 + ni * 16 + (l & 15);
            bf16x8 bfv = *(const bf16x8*)((char*)Mb + trow * 512 + (kb ^ ((trow & 7) << 4)));
            acc[ni] = __builtin_amdgcn_mfma_f32_16x16x32_bf16(af, bfv, acc[ni], 0, 0, 0);
        }
    }
    __syncthreads();   // all MFMA reads done; reuse Mb region for P

#pragma unroll
    for (int ni = 0; ni < 2; ++ni)
#pragma unroll
        for (int j = 0; j < 4; ++j) {
            int rowp = wr * 16 + (l >> 4) * 4 + j;          // s-local
            int colp = wc * 32 + ni * 16 + (l & 15);        // t
            P[rowp * 97 + colp] = acc[ni][j];
        }
    __syncthreads();

    if (tid < 384) {
        int r = tid >> 3, j = tid & 7;
        float m = -1e30f;
        for (int t = j; t < Tq; t += 8) m = fmaxf(m, P[r * 97 + t]);
        m = fmaxf(m, __shfl_xor(m, 1));
        m = fmaxf(m, __shfl_xor(m, 2));
        m = fmaxf(m, __shfl_xor(m, 4));
        float s = 0.f;
        for (int t = j; t < Tq; t += 8) s += __expf(P[r * 97 + t] - m);
        s += __shfl_xor(s, 1);
        s += __shfl_xor(s, 2);
        s += __shfl_xor(s, 4);
        if (j == 0) { mxs[r] = m; rds[r] = 1.f / s; }
    }
    __syncthreads();

    for (int j = tid; j < EAq; j += 576) {
        int s  = esrc[(size_t)b * EAq + j];
        int dt = edst[(size_t)b * EAq + j];
        int r  = etype[(size_t)b * EAq + j];
        int sl = s - s0;
        if ((unsigned)sl < 48u) {
            float v = __expf(P[sl * 97 + dt] - mxs[sl]) * rds[sl];
            atomicAdd(&A2f[((size_t)b * 96 + dt) * KAq + r * 96 + s], v);
        }
    }
    if (s0 == 0) {
        for (int j = tid; j < Tq * Oq; j += 576) {
            int t = j / Oq, o = j % Oq;
            A2f[((size_t)b * 96 + Tq + o) * KAq + (Rq - 1) * 96 + t] =
                natt[(size_t)b * (Tq * Oq) + j];
        }
    }
}

// ---------------- xwT[kk][n'] = sum_d WT[kk][d] * xb[n'][d]  (bf16 MFMA, 128x64, BK=64, dbuf)
__global__ __launch_bounds__(256) void k_gemm1(const unsigned short* __restrict__ Wt,
                                               const unsigned short* __restrict__ xb,
                                               unsigned short* __restrict__ xwT) {
    __shared__ float4 lds4[2][1536];    // per buf (24KB): A 128x64 @0 (16KB), B 64x64 @16384 (8KB)
    const int tid = threadIdx.x;
    const int m0 = blockIdx.x * 128, n0 = blockIdx.y * 64;
    const int w = tid >> 6, l = tid & 63;
    const int wr = w >> 1, wc = w & 1;   // wave grid 2x2: wave owns 64(m) x 32(n)

    f32x4 acc[4][2];
#pragma unroll
    for (int i = 0; i < 4; ++i)
#pragma unroll
        for (int j = 0; j < 2; ++j) acc[i][j] = (f32x4)0.0f;

    char* const lbase0 = (char*)&lds4[0][0];
    char* const lbase1 = lbase0 + 24576;

    auto stage = [&](char* base, int k0) {
#pragma unroll
        for (int i = 0; i < 4; ++i) {            // A: 1024 chunks
            int idx = i * 256 + tid;
            int row = idx >> 3;
            int csrc = (idx & 7) ^ (row & 7);
            const unsigned short* g = Wt + (size_t)(m0 + row) * Dq + k0 + csrc * 8;
            char* ld = base + i * 4096 + w * 1024;
            __builtin_amdgcn_global_load_lds((gu32*)g, (lu32*)(unsigned int)(uintptr_t)ld, 16, 0, 0);
        }
#pragma unroll
        for (int i = 0; i < 2; ++i) {            // B: 512 chunks
            int idx = i * 256 + tid;
            int row = idx >> 3;
            int csrc = (idx & 7) ^ (row & 7);
            const unsigned short* g = xb + (size_t)(n0 + row) * Dq + k0 + csrc * 8;
            char* ld = base + 16384 + i * 4096 + w * 1024;
            __builtin_amdgcn_global_load_lds((gu32*)g, (lu32*)(unsigned int)(uintptr_t)ld, 16, 0, 0);
        }
    };

    stage(lbase0, 0);
    __syncthreads();

    int cur = 0;
    for (int t = 0; t < Dq / 64; ++t) {
        char* base = cur ? lbase1 : lbase0;
        if (t < Dq / 64 - 1) stage(cur ? lbase0 : lbase1, (t + 1) * 64);

        bf16x8 af[4][2], bfr[2][2];
#pragma unroll
        for (int ks = 0; ks < 2; ++ks) {
            int koff = ks * 64 + (l >> 4) * 16;
#pragma unroll
            for (int mi = 0; mi < 4; ++mi) {
                int row = wr * 64 + mi * 16 + (l & 15);
                af[mi][ks] = *(const bf16x8*)(base + row * 128 + (koff ^ ((row & 7) << 4)));
            }
#pragma unroll
            for (int ni = 0; ni < 2; ++ni) {
                int row = wc * 32 + ni * 16 + (l & 15);
                bfr[ni][ks] = *(const bf16x8*)(base + 16384 + row * 128 + (koff ^ ((row & 7) << 4)));
            }
        }
#pragma unroll
        for (int ks = 0; ks < 2; ++ks)
#pragma unroll
            for (int mi = 0; mi < 4; ++mi)
#pragma unroll
                for (int ni = 0; ni < 2; ++ni)
                    acc[mi][ni] = __builtin_amdgcn_mfma_f32_16x16x32_bf16(
                        af[mi][ks], bfr[ni][ks], acc[mi][ni], 0, 0, 0);
        __syncthreads();
        cur ^= 1;
    }

    // epilogue: per-wave [64][33] fp32 scratch -> row-contiguous bf16 stores
    float* epi = (float*)lbase0 + w * 2112;      // 64*33 floats per wave (8448B), 4 waves = 33KB
#pragma unroll
    for (int mi = 0; mi < 4; ++mi)
#pragma unroll
        for (int ni = 0; ni < 2; ++ni)
#pragma unroll
            for (int j = 0; j < 4; ++j) {
                int row = mi * 16 + (l >> 4) * 4 + j;
                int col = ni * 16 + (l & 15);
                epi[row * 33 + col] = acc[mi][ni][j];
            }
    unsigned short* dst = xwT + (size_t)(m0 + wr * 64 + l) * NPq + n0 + wc * 32;
#pragma unroll
    for (int q = 0; q < 4; ++q) {
        u16x8 o;
#pragma unroll
        for (int e = 0; e < 8; ++e) o[e] = f2bf(epi[l * 33 + q * 8 + e]);
        *(u16x8*)(dst + q * 8) = o;
    }
}

// ---------------- out[b*95+nl][h] = sum_k A2(fp32->bf16 lean-staged) * Ychunk + root + bias
__global__ __launch_bounds__(256) void k_gemm2(const float* __restrict__ A2f,
                                               const unsigned short* __restrict__ xwT,
                                               const float* __restrict__ bias,
                                               float* __restrict__ out) {
    __shared__ char lds[2][30720];      // per buf: A 96x96 bf16 (18432) + Y 64x96 bf16 (12288)
    const int tid = threadIdx.x;
    const int b = blockIdx.x;
    const int h0 = blockIdx.y * 64;
    const int w = tid >> 6, l = tid & 63;
    const int wr = w >> 1, wc = w & 1;

    f32x4 acc[3][2];
#pragma unroll
    for (int i = 0; i < 3; ++i)
#pragma unroll
        for (int j = 0; j < 2; ++j) acc[i][j] = (f32x4)0.0f;

    float4 a0[5], a1[5];                // lean staging regs, one set only
    auto loadA = [&](int r) {
#pragma unroll
        for (int i = 0; i < 5; ++i) {
            unsigned idx = tid + i * 256;
            if (idx < 1152) {
                unsigned row = idx / 12, u = idx - row * 12;
                const float4* s4 = (const float4*)(A2f + ((size_t)b * 96 + row) * KAq + r * 96 + u * 8);
                a0[i] = s4[0];
                a1[i] = s4[1];
            }
        }
    };
    auto writeA = [&](char* base) {
#pragma unroll
        for (int i = 0; i < 5; ++i) {
            unsigned idx = tid + i * 256;
            if (idx < 1152) {
                unsigned row = idx / 12, u = idx - row * 12;
                u16x8 pk;
                pk[0] = f2bf(a0[i].x); pk[1] = f2bf(a0[i].y);
                pk[2] = f2bf(a0[i].z); pk[3] = f2bf(a0[i].w);
                pk[4] = f2bf(a1[i].x); pk[5] = f2bf(a1[i].y);
                pk[6] = f2bf(a1[i].z); pk[7] = f2bf(a1[i].w);
                *(u16x8*)(base + row * 192 + ((u ^ (row & 3)) * 16)) = pk;
            }
        }
    };
    auto stageY = [&](int buf, int r) {
        char* base = &lds[buf][0];
#pragma unroll
        for (int i = 0; i < 3; ++i) {
            unsigned idx = tid + i * 256;
            unsigned row = idx / 12, u = idx - row * 12;
            unsigned usw = u ^ (row & 3);
            const unsigned short* g = xwT + (size_t)(r * 256 + h0 + row) * NPq + b * 96 + usw * 8;
            __builtin_amdgcn_global_load_lds((gu32*)g,
                (lu32*)(unsigned int)(uintptr_t)(base + 18432 + idx * 16), 16, 0, 0);
        }
    };

    loadA(0);
    writeA(&lds[0][0]);
    stageY(0, 0);
    __syncthreads();
    int cur = 0;
    for (int r = 0; r < 5; ++r) {
        char* base = &lds[cur][0];
        if (r < 4) { loadA(r + 1); stageY(cur ^ 1, r + 1); }   // issue loads early
        bf16x8 af[3], bfv[2];
#pragma unroll
        for (int ks = 0; ks < 3; ++ks) {
            int kb = ks * 64 + (l >> 4) * 16;
#pragma unroll
            for (int mi = 0; mi < 3; ++mi) {
                int row = wr * 48 + mi * 16 + (l & 15);
                af[mi] = *(const bf16x8*)(base + row * 192 + (kb ^ ((row & 3) << 4)));
            }
#pragma unroll
            for (int ni = 0; ni < 2; ++ni) {
                int row = wc * 32 + ni * 16 + (l & 15);
                bfv[ni] = *(const bf16x8*)(base + 18432 + row * 192 + (kb ^ ((row & 3) << 4)));
            }
#pragma unroll
            for (int mi = 0; mi < 3; ++mi)
#pragma unroll
                for (int ni = 0; ni < 2; ++ni)
                    acc[mi][ni] = __builtin_amdgcn_mfma_f32_16x16x32_bf16(
                        af[mi], bfv[ni], acc[mi][ni], 0, 0, 0);
        }
        if (r < 4) writeA(&lds[cur ^ 1][0]);                   // cvt+write late
        __syncthreads();
        cur ^= 1;
    }

#pragma unroll
    for (int mi = 0; mi < 3; ++mi) {
        int mrow = wr * 48 + mi * 16 + (l >> 4) * 4;
#pragma unroll
        for (int ni = 0; ni < 2; ++ni) {
            int n = h0 + wc * 32 + ni * 16 + (l & 15);
            float bv = bias[n];
            ushort4 rt = *(const ushort4*)(xwT + (size_t)(Rq * 256 + n) * NPq + b * 96 + mrow);
#pragma unroll
            for (int j = 0; j < 4; ++j) {
                int m = mrow + j;
                float rv = bf2f(j == 0 ? rt.x : j == 1 ? rt.y : j == 2 ? rt.z : rt.w);
                if (m < NPGq)
                    out[((size_t)b * NPGq + m) * Hq + n] = acc[mi][ni][j] + rv + bv;
            }
        }
    }
}

extern "C" void kernel_launch(void* const* d_in, const int* in_sizes, int n_in,
                              void* d_out, int out_size, void* d_ws, size_t ws_size,
                              hipStream_t stream) {
    (void)in_sizes; (void)n_in; (void)out_size; (void)ws_size;
    const float* M     = (const float*)d_in[0];
    const float* x     = (const float*)d_in[1];
    const float* natt  = (const float*)d_in[2];
    const float* Ws    = (const float*)d_in[3];
    const float* bases = (const float*)d_in[4];
    const float* comp  = (const float*)d_in[5];
    const float* rootw = (const float*)d_in[6];
    const float* bias  = (const float*)d_in[7];
    const int* esrc    = (const int*)d_in[8];
    const int* edst    = (const int*)d_in[9];
    const int* etype   = (const int*)d_in[10];
    float* out = (float*)d_out;
    char* ws = (char*)d_ws;

    unsigned short* Wt  = (unsigned short*)(ws + 0);          //    786,432 B
    float* A2f   = (float*)(ws + 786432);                     // 11,796,480 B
    unsigned short* xb  = (unsigned short*)(ws + 12582912);   //  3,145,728 B
    unsigned short* xwT = (unsigned short*)(ws + 15728640);   // 18,874,368 B (total ~34.6 MB)

    k_prep<<<dim3(3696), 256, 0, stream>>>(x, bases, comp, rootw, xb, Wt, A2f);
    k_attn<<<dim3(Bq * 2), 576, 0, stream>>>(M, Ws, natt, esrc, edst, etype, A2f);
    k_gemm1<<<dim3(KKq / 128, NPq / 64), 256, 0, stream>>>(Wt, xb, xwT);
    k_gemm2<<<dim3(Bq, Hq / 64), 256, 0, stream>>>(A2f, xwT, bias, out);
}

// Round 11
// 65.785 us; speedup vs baseline: 1.0898x; 1.0898x over previous
//
#include <hip/hip_runtime.h>
#include <cstddef>
#include <cstdint>

#define Bq 64
#define Tq 90
#define Oq 5
#define Dq 256
#define Hq 256
#define EAq 4096
#define Rq 5
#define NBq 8
#define NPGq 95
#define Nq 6080           // B*NPG real nodes
#define NPq 6144          // padded node space: 64 graphs x 96
#define EPBq 4546         // EA + T*O
#define Eq 290944         // B*EPB
#define KAq 480           // A2 cols: 5 relations x 96

typedef __attribute__((ext_vector_type(8))) short bf16x8;
typedef __attribute__((ext_vector_type(8))) unsigned short u16x8;
typedef __attribute__((ext_vector_type(4))) float f32x4;
typedef __attribute__((address_space(1))) const unsigned int gu32;
typedef __attribute__((address_space(3))) unsigned int lu32;

__device__ __forceinline__ unsigned short f2bf(float f) {
    unsigned u = __float_as_uint(f);
    unsigned r = (u + 0x7FFF + ((u >> 16) & 1)) >> 16;
    return (unsigned short)r;
}
__device__ __forceinline__ float bf2f(unsigned short s) {
    return __uint_as_float(((unsigned)s) << 16);
}

// ---------------- fused prep:
// blocks 0..2879: zero A2f; 2880..3647: x->xb bf16; 3648..3695: Wt compute
__global__ __launch_bounds__(256) void k_prep(const float* __restrict__ x,
                                              const float* __restrict__ bases,
                                              const float* __restrict__ comp,
                                              const float* __restrict__ rootw,
                                              unsigned short* __restrict__ xb,
                                              unsigned short* __restrict__ Wt,
                                              float* __restrict__ A2f) {
    __shared__ float Ld[32][257];
    int blk = blockIdx.x;
    if (blk < 2880) {
        unsigned i = blk * 256 + threadIdx.x;       // 737280 float4s == 11,796,480 B
        ((float4*)A2f)[i] = make_float4(0.f, 0.f, 0.f, 0.f);
        return;
    }
    if (blk < 3648) {
        unsigned i = (blk - 2880) * 256 + threadIdx.x;  // over NPq*32 chunks of 8
        unsigned np = i >> 5, c = i & 31;
        unsigned s = np % 96;
        u16x8 pk;
        if (s == 95) {
#pragma unroll
            for (int q = 0; q < 8; ++q) pk[q] = 0;
        } else {
            unsigned node = np - np / 96;
            const float4* xs = (const float4*)(x + (size_t)node * Dq + c * 8);
            float4 a = xs[0], b2 = xs[1];
            pk[0] = f2bf(a.x);  pk[1] = f2bf(a.y);  pk[2] = f2bf(a.z);  pk[3] = f2bf(a.w);
            pk[4] = f2bf(b2.x); pk[5] = f2bf(b2.y); pk[6] = f2bf(b2.z); pk[7] = f2bf(b2.w);
        }
        *(u16x8*)(xb + (size_t)np * Dq + c * 8) = pk;
        return;
    }
    // Wt: WT[kk][d] bf16; kk=r*256+h or 1280+h (root)
    int wblk = blk - 3648;            // 0..47
    int rs = wblk >> 3;               // 0..5
    int d0 = (wblk & 7) * 32;
    int t = threadIdx.x;              // h
    float cmp[NBq];
    if (rs < Rq)
#pragma unroll
        for (int nb = 0; nb < NBq; ++nb) cmp[nb] = comp[rs * NBq + nb];
    for (int dl = 0; dl < 32; ++dl) {
        int d = d0 + dl;
        float v;
        if (rs < Rq) {
            v = 0.f;
#pragma unroll
            for (int nb = 0; nb < NBq; ++nb)
                v += cmp[nb] * bases[((size_t)nb * Dq + d) * Hq + t];
        } else {
            v = rootw[(size_t)d * Hq + t];
        }
        Ld[dl][t] = v;
    }
    __syncthreads();
    int c = t & 31, hg = t >> 5;
    for (int hh = 0; hh < 32; ++hh) {
        int h = hg * 32 + hh;
        Wt[(size_t)(rs * 256 + h) * Dq + d0 + c] = f2bf(Ld[c][h]);
    }
}

// ---------------- fused: P_b = M_b @ Ws^T (bf16 MFMA, 9 waves, 32x32 quadrants),
//                  column softmax, scatter edge norms into A2f[b] in-block  (R8 structure)
__global__ __launch_bounds__(576) void k_attn(const float* __restrict__ M,
                                              const float* __restrict__ Ws,
                                              const float* __restrict__ natt,
                                              const int* __restrict__ esrc,
                                              const int* __restrict__ edst,
                                              const int* __restrict__ etype,
                                              float* __restrict__ A2f) {
    __shared__ __attribute__((aligned(16))) char lds[99072];
    unsigned short* Mb = (unsigned short*)lds;           // [96][256] bf16, swizzled (48KB)
    unsigned short* Wb = (unsigned short*)(lds + 49152); // [96][256] bf16, swizzled (48KB)
    float* P   = (float*)lds;                            // [96][97] fp32 (reuses Mb region)
    float* mxs = (float*)(lds + 98304);                  // [96]
    float* rds = (float*)(lds + 98688);                  // [96]
    const int b = blockIdx.x;
    const int tid = threadIdx.x;

#pragma unroll
    for (int i = 0; i < 6; ++i) {
        int idx = tid + i * 576;            // 0..3455, want 0..3071
        if (idx < 3072) {
            int row = idx >> 5, c = idx & 31;
            u16x8 pm, pw;
            if (row < Tq) {
                const float4* ms = (const float4*)(M + ((size_t)b * Tq + row) * Dq + c * 8);
                float4 a0 = ms[0], a1 = ms[1];
                pm[0] = f2bf(a0.x); pm[1] = f2bf(a0.y); pm[2] = f2bf(a0.z); pm[3] = f2bf(a0.w);
                pm[4] = f2bf(a1.x); pm[5] = f2bf(a1.y); pm[6] = f2bf(a1.z); pm[7] = f2bf(a1.w);
                const float4* ws = (const float4*)(Ws + (size_t)row * Dq + c * 8);
                float4 w0 = ws[0], w1 = ws[1];
                pw[0] = f2bf(w0.x); pw[1] = f2bf(w0.y); pw[2] = f2bf(w0.z); pw[3] = f2bf(w0.w);
                pw[4] = f2bf(w1.x); pw[5] = f2bf(w1.y); pw[6] = f2bf(w1.z); pw[7] = f2bf(w1.w);
            } else {
#pragma unroll
                for (int q = 0; q < 8; ++q) { pm[q] = 0; pw[q] = 0; }
            }
            int off = row * 512 + ((c * 16) ^ ((row & 7) << 4));
            *(u16x8*)((char*)Mb + off) = pm;
            *(u16x8*)((char*)Wb + off) = pw;
        }
    }
    __syncthreads();

    const int w = tid >> 6, l = tid & 63;
    const int wr = w / 3, wc = w % 3;
    f32x4 acc[2][2];
#pragma unroll
    for (int i = 0; i < 2; ++i)
#pragma unroll
        for (int j = 0; j < 2; ++j) acc[i][j] = (f32x4)0.0f;
#pragma unroll
    for (int ks = 0; ks < 8; ++ks) {
        int kb = ks * 64 + (l >> 4) * 16;
        bf16x8 af[2], bfv[2];
#pragma unroll
        for (int mi = 0; mi < 2; ++mi) {
            int row = wr * 32 + mi * 16 + (l & 15);
            af[mi] = *(const bf16x8*)((char*)Mb + row * 512 + (kb ^ ((row & 7) << 4)));
        }
#pragma unroll
        for (int ni = 0; ni < 2; ++ni) {
            int row = wc * 32 + ni * 16 + (l & 15);
            bfv[ni] = *(const bf16x8*)((char*)Wb + row * 512 + (kb ^ ((row & 7) << 4)));
        }
#pragma unroll
        for (int mi = 0; mi < 2; ++mi)
#pragma unroll
            for (int ni = 0; ni < 2; ++ni)
                acc[mi][ni] = __builtin_amdgcn_mfma_f32_16x16x32_bf16(
                    af[mi], bfv[ni], acc[mi][ni], 0, 0, 0);
    }
    __syncthreads();   // all MFMA reads of Mb/Wb done; reuse region for P

#pragma unroll
    for (int mi = 0; mi < 2; ++mi)
#pragma unroll
        for (int ni = 0; ni < 2; ++ni)
#pragma unroll
            for (int j = 0; j < 4; ++j) {
                int rowp = wr * 32 + mi * 16 + (l >> 4) * 4 + j;
                int colp = wc * 32 + ni * 16 + (l & 15);
                P[rowp * 97 + colp] = acc[mi][ni][j];
            }
    __syncthreads();

    if (tid < 96) {
        float m = -1e30f;
        for (int t = 0; t < Tq; ++t) m = fmaxf(m, P[t * 97 + tid]);
        float s = 0.f;
        for (int t = 0; t < Tq; ++t) s += __expf(P[t * 97 + tid] - m);
        mxs[tid] = m;
        rds[tid] = 1.f / s;
    }
    __syncthreads();

    // edge scatter for this graph (4546 edges, 8 iters/thread)
    for (int j = tid; j < EPBq; j += 576) {
        if (j < EAq) {
            int s  = esrc[(size_t)b * EAq + j];
            int dt = edst[(size_t)b * EAq + j];
            int r  = etype[(size_t)b * EAq + j];
            float v = __expf(P[dt * 97 + s] - mxs[s]) * rds[s];
            atomicAdd(&A2f[((size_t)b * 96 + dt) * KAq + r * 96 + s], v);
        } else {
            int i = j - EAq;
            int t = i / Oq, o = i % Oq;
            A2f[((size_t)b * 96 + Tq + o) * KAq + (Rq - 1) * 96 + t] =
                natt[(size_t)b * (Tq * Oq) + i];
        }
    }
}

// ---------------- fused per-graph back-half:
// block (hc, b): acc[96 nl][64 h] = sum_r A2_r @ (W_r-chunk @ X_b^T)^T + root + bias
__global__ __launch_bounds__(512) void k_gemm3(const float* __restrict__ A2f,
                                               const unsigned short* __restrict__ Wt,
                                               const unsigned short* __restrict__ xb,
                                               const float* __restrict__ bias,
                                               float* __restrict__ out) {
    __shared__ __attribute__((aligned(16))) char lds[112640];
    char* const Xs  = lds;              // [96][512B]  swizzled bf16   48KB
    char* const Wl  = lds + 49152;      // [64][512B]  swizzled bf16   32KB
    char* const Ztl = lds + 81920;      // [64][192B]  swizzled bf16   12KB
    char* const A2l = lds + 94208;      // [96][192B]  swizzled bf16   18KB
    const int hc = blockIdx.x;          // 0..3
    const int b  = blockIdx.y;          // 0..63
    const int tid = threadIdx.x;
    const int w = tid >> 6, l = tid & 63;
    const int wrz = w >> 1, wcz = w & 1;   // gemm-Z grid: 4(h) x 2(s)
    const int wrn = w >> 2, wcn = w & 3;   // gemm-out grid: 2(nl) x 4(h)

    // stage X_b once (3072 chunks, 6 iters)
#pragma unroll
    for (int i = 0; i < 6; ++i) {
        int idx = i * 512 + tid;
        int row = idx >> 5, c = idx & 31;
        const unsigned short* g = xb + (size_t)(b * 96 + row) * Dq + (c ^ (row & 7)) * 8;
        __builtin_amdgcn_global_load_lds((gu32*)g,
            (lu32*)(unsigned int)(uintptr_t)(Xs + idx * 16), 16, 0, 0);
    }

    f32x4 acc[3];
#pragma unroll
    for (int i = 0; i < 3; ++i) acc[i] = (f32x4)0.0f;

    auto stageW = [&](int kkbase) {   // W rows kkbase..kkbase+63, 2048 chunks, 4 iters
#pragma unroll
        for (int i = 0; i < 4; ++i) {
            int idx = i * 512 + tid;
            int hrow = idx >> 5, c = idx & 31;
            const unsigned short* g = Wt + (size_t)(kkbase + hrow) * Dq + (c ^ (hrow & 7)) * 8;
            __builtin_amdgcn_global_load_lds((gu32*)g,
                (lu32*)(unsigned int)(uintptr_t)(Wl + idx * 16), 16, 0, 0);
        }
    };
    auto gemmZ = [&](f32x4 (&zacc)[3]) {   // Zt pre-write: zacc[ni] over (16h x 48s)
#pragma unroll
        for (int i = 0; i < 3; ++i) zacc[i] = (f32x4)0.0f;
#pragma unroll
        for (int ks = 0; ks < 8; ++ks) {
            int kb = ks * 64 + (l >> 4) * 16;
            int hl = wrz * 16 + (l & 15);
            bf16x8 af = *(const bf16x8*)(Wl + hl * 512 + (kb ^ ((hl & 7) << 4)));
#pragma unroll
            for (int ni = 0; ni < 3; ++ni) {
                int s = wcz * 48 + ni * 16 + (l & 15);
                bf16x8 xv = *(const bf16x8*)(Xs + s * 512 + (kb ^ ((s & 7) << 4)));
                zacc[ni] = __builtin_amdgcn_mfma_f32_16x16x32_bf16(af, xv, zacc[ni], 0, 0, 0);
            }
        }
    };
    auto writeZt = [&](f32x4 (&zacc)[3]) {
#pragma unroll
        for (int ni = 0; ni < 3; ++ni)
#pragma unroll
            for (int j = 0; j < 4; ++j) {
                int h = wrz * 16 + (l >> 4) * 4 + j;
                int s = wcz * 48 + ni * 16 + (l & 15);
                *(unsigned short*)(Ztl + h * 192 + (((s >> 3) ^ (h & 3)) << 4) + (s & 7) * 2)
                    = f2bf(zacc[ni][j]);
            }
    };

    for (int r = 0; r < Rq; ++r) {
        stageW(r * 256 + hc * 64);
        // stage A2_r: fp32 -> bf16, 1152 items (row, 8-float chunk u)
#pragma unroll
        for (int i = 0; i < 3; ++i) {
            int idx = i * 512 + tid;
            if (idx < 1152) {
                int row = idx / 12, u = idx - row * 12;
                const float4* s4 = (const float4*)(A2f + ((size_t)b * 96 + row) * KAq + r * 96 + u * 8);
                float4 p0 = s4[0], p1 = s4[1];
                u16x8 pk;
                pk[0] = f2bf(p0.x); pk[1] = f2bf(p0.y); pk[2] = f2bf(p0.z); pk[3] = f2bf(p0.w);
                pk[4] = f2bf(p1.x); pk[5] = f2bf(p1.y); pk[6] = f2bf(p1.z); pk[7] = f2bf(p1.w);
                *(u16x8*)(A2l + row * 192 + ((u ^ (row & 3)) << 4)) = pk;
            }
        }
        __syncthreads();      // Xs (r==0), Wl, A2l ready
        f32x4 zacc[3];
        gemmZ(zacc);
        writeZt(zacc);
        __syncthreads();      // Ztl ready
        // acc[nl][h] += A2_r @ Zt^T : K = 96 s
#pragma unroll
        for (int ks = 0; ks < 3; ++ks) {
            int kb = ks * 64 + (l >> 4) * 16;
            int h = wcn * 16 + (l & 15);
            bf16x8 bfv = *(const bf16x8*)(Ztl + h * 192 + (kb ^ ((h & 3) << 4)));
#pragma unroll
            for (int mi = 0; mi < 3; ++mi) {
                int nl = wrn * 48 + mi * 16 + (l & 15);
                bf16x8 af = *(const bf16x8*)(A2l + nl * 192 + (kb ^ ((nl & 3) << 4)));
                acc[mi] = __builtin_amdgcn_mfma_f32_16x16x32_bf16(af, bfv, acc[mi], 0, 0, 0);
            }
        }
        __syncthreads();      // before next r overwrites Wl/A2l/Ztl
    }

    // root term: Z5 = root-chunk @ X^T, add Z5t[h][nl] elementwise
    stageW(Rq * 256 + hc * 64);
    __syncthreads();
    f32x4 zacc[3];
    gemmZ(zacc);
    writeZt(zacc);
    __syncthreads();
#pragma unroll
    for (int mi = 0; mi < 3; ++mi) {
        int h = wcn * 16 + (l & 15);
#pragma unroll
        for (int j = 0; j < 4; ++j) {
            int nl = wrn * 48 + mi * 16 + (l >> 4) * 4 + j;
            float rv = bf2f(*(const unsigned short*)(Ztl + h * 192 +
                            (((nl >> 3) ^ (h & 3)) << 4) + (nl & 7) * 2));
            acc[mi][j] += rv;
        }
    }

    // store out + bias
    {
        int h = wcn * 16 + (l & 15);
        float bv = bias[hc * 64 + h];
#pragma unroll
        for (int mi = 0; mi < 3; ++mi)
#pragma unroll
            for (int j = 0; j < 4; ++j) {
                int nl = wrn * 48 + mi * 16 + (l >> 4) * 4 + j;
                if (nl < NPGq)
                    out[((size_t)b * NPGq + nl) * Hq + hc * 64 + h] = acc[mi][j] + bv;
            }
    }
}

extern "C" void kernel_launch(void* const* d_in, const int* in_sizes, int n_in,
                              void* d_out, int out_size, void* d_ws, size_t ws_size,
                              hipStream_t stream) {
    (void)in_sizes; (void)n_in; (void)out_size; (void)ws_size;
    const float* M     = (const float*)d_in[0];
    const float* x     = (const float*)d_in[1];
    const float* natt  = (const float*)d_in[2];
    const float* Ws    = (const float*)d_in[3];
    const float* bases = (const float*)d_in[4];
    const float* comp  = (const float*)d_in[5];
    const float* rootw = (const float*)d_in[6];
    const float* bias  = (const float*)d_in[7];
    const int* esrc    = (const int*)d_in[8];
    const int* edst    = (const int*)d_in[9];
    const int* etype   = (const int*)d_in[10];
    float* out = (float*)d_out;
    char* ws = (char*)d_ws;

    unsigned short* Wt  = (unsigned short*)(ws + 0);          //    786,432 B
    float* A2f   = (float*)(ws + 786432);                     // 11,796,480 B
    unsigned short* xb  = (unsigned short*)(ws + 12582912);   //  3,145,728 B (total ~15.7 MB)

    k_prep<<<dim3(3696), 256, 0, stream>>>(x, bases, comp, rootw, xb, Wt, A2f);
    k_attn<<<dim3(Bq), 576, 0, stream>>>(M, Ws, natt, esrc, edst, etype, A2f);
    k_gemm3<<<dim3(4, Bq), 512, 0, stream>>>(A2f, Wt, xb, bias, out);
}

// Round 12
// 61.566 us; speedup vs baseline: 1.1644x; 1.0685x over previous
//
#include <hip/hip_runtime.h>
#include <cstddef>
#include <cstdint>

#define Bq 64
#define Tq 90
#define Oq 5
#define Dq 256
#define Hq 256
#define EAq 4096
#define Rq 5
#define NBq 8
#define NPGq 95
#define Nq 6080           // B*NPG real nodes
#define NPq 6144          // padded node space: 64 graphs x 96
#define EPBq 4546         // EA + T*O
#define Eq 290944         // B*EPB
#define KKq 1536          // (R+1)*D rows of WT / xwT
#define KAq 480           // A2 cols: 5 relations x 96

typedef __attribute__((ext_vector_type(8))) short bf16x8;
typedef __attribute__((ext_vector_type(8))) unsigned short u16x8;
typedef __attribute__((ext_vector_type(4))) float f32x4;
typedef __attribute__((address_space(1))) const unsigned int gu32;
typedef __attribute__((address_space(3))) unsigned int lu32;

__device__ __forceinline__ unsigned short f2bf(float f) {
    unsigned u = __float_as_uint(f);
    unsigned r = (u + 0x7FFF + ((u >> 16) & 1)) >> 16;
    return (unsigned short)r;
}
__device__ __forceinline__ float bf2f(unsigned short s) {
    return __uint_as_float(((unsigned)s) << 16);
}

// ---------------- fused prep:
// blocks 0..2879: zero A2f; 2880..3647: x->xb bf16; 3648..3695: Wt compute
__global__ __launch_bounds__(256) void k_prep(const float* __restrict__ x,
                                              const float* __restrict__ bases,
                                              const float* __restrict__ comp,
                                              const float* __restrict__ rootw,
                                              unsigned short* __restrict__ xb,
                                              unsigned short* __restrict__ Wt,
                                              float* __restrict__ A2f) {
    __shared__ float Ld[32][257];
    int blk = blockIdx.x;
    if (blk < 2880) {
        unsigned i = blk * 256 + threadIdx.x;       // 737280 float4s == 11,796,480 B
        ((float4*)A2f)[i] = make_float4(0.f, 0.f, 0.f, 0.f);
        return;
    }
    if (blk < 3648) {
        unsigned i = (blk - 2880) * 256 + threadIdx.x;  // over NPq*32 chunks of 8
        unsigned np = i >> 5, c = i & 31;
        unsigned s = np % 96;
        u16x8 pk;
        if (s == 95) {
#pragma unroll
            for (int q = 0; q < 8; ++q) pk[q] = 0;
        } else {
            unsigned node = np - np / 96;
            const float4* xs = (const float4*)(x + (size_t)node * Dq + c * 8);
            float4 a = xs[0], b2 = xs[1];
            pk[0] = f2bf(a.x);  pk[1] = f2bf(a.y);  pk[2] = f2bf(a.z);  pk[3] = f2bf(a.w);
            pk[4] = f2bf(b2.x); pk[5] = f2bf(b2.y); pk[6] = f2bf(b2.z); pk[7] = f2bf(b2.w);
        }
        *(u16x8*)(xb + (size_t)np * Dq + c * 8) = pk;
        return;
    }
    // Wt: WT[kk][d] bf16; kk=r*256+h or 1280+h (root)
    int wblk = blk - 3648;            // 0..47
    int rs = wblk >> 3;               // 0..5
    int d0 = (wblk & 7) * 32;
    int t = threadIdx.x;              // h
    float cmp[NBq];
    if (rs < Rq)
#pragma unroll
        for (int nb = 0; nb < NBq; ++nb) cmp[nb] = comp[rs * NBq + nb];
    for (int dl = 0; dl < 32; ++dl) {
        int d = d0 + dl;
        float v;
        if (rs < Rq) {
            v = 0.f;
#pragma unroll
            for (int nb = 0; nb < NBq; ++nb)
                v += cmp[nb] * bases[((size_t)nb * Dq + d) * Hq + t];
        } else {
            v = rootw[(size_t)d * Hq + t];
        }
        Ld[dl][t] = v;
    }
    __syncthreads();
    int c = t & 31, hg = t >> 5;
    for (int hh = 0; hh < 32; ++hh) {
        int h = hg * 32 + hh;
        Wt[(size_t)(rs * 256 + h) * Dq + d0 + c] = f2bf(Ld[c][h]);
    }
}

// ---------------- fused main: blocks 0..63 = attn(graph b); blocks 64..1215 = gemm1 tile
__global__ __launch_bounds__(576) void k_main(const float* __restrict__ M,
                                              const float* __restrict__ Ws,
                                              const float* __restrict__ natt,
                                              const int* __restrict__ esrc,
                                              const int* __restrict__ edst,
                                              const int* __restrict__ etype,
                                              float* __restrict__ A2f,
                                              const unsigned short* __restrict__ Wt,
                                              const unsigned short* __restrict__ xb,
                                              unsigned short* __restrict__ xwT) {
    __shared__ __attribute__((aligned(16))) char lds[99072];
    const int tid = threadIdx.x;
    const int w = tid >> 6, l = tid & 63;

    if (blockIdx.x < 64) {
        // ======================= ATTN PATH (R11-proven, + edge-index hoist) ==========
        unsigned short* Mb = (unsigned short*)lds;           // [96][256] bf16 swz (48KB)
        unsigned short* Wb = (unsigned short*)(lds + 49152); // [96][256] bf16 swz (48KB)
        float* P   = (float*)lds;                            // [96][97] fp32 (reuses Mb)
        float* mxs = (float*)(lds + 98304);                  // [96]
        float* rds = (float*)(lds + 98688);                  // [96]
        const int b = blockIdx.x;

        // hoist edge indices: loads issue now, waited on at scatter (latency hidden)
        int es[8], ed[8], et[8];
#pragma unroll
        for (int k = 0; k < 8; ++k) {
            int j = tid + k * 576;
            if (j < EAq) {
                es[k] = esrc[(size_t)b * EAq + j];
                ed[k] = edst[(size_t)b * EAq + j];
                et[k] = etype[(size_t)b * EAq + j];
            }
        }

#pragma unroll
        for (int i = 0; i < 6; ++i) {
            int idx = tid + i * 576;            // 0..3455, want 0..3071
            if (idx < 3072) {
                int row = idx >> 5, c = idx & 31;
                u16x8 pm, pw;
                if (row < Tq) {
                    const float4* ms = (const float4*)(M + ((size_t)b * Tq + row) * Dq + c * 8);
                    float4 a0 = ms[0], a1 = ms[1];
                    pm[0] = f2bf(a0.x); pm[1] = f2bf(a0.y); pm[2] = f2bf(a0.z); pm[3] = f2bf(a0.w);
                    pm[4] = f2bf(a1.x); pm[5] = f2bf(a1.y); pm[6] = f2bf(a1.z); pm[7] = f2bf(a1.w);
                    const float4* ws = (const float4*)(Ws + (size_t)row * Dq + c * 8);
                    float4 w0 = ws[0], w1 = ws[1];
                    pw[0] = f2bf(w0.x); pw[1] = f2bf(w0.y); pw[2] = f2bf(w0.z); pw[3] = f2bf(w0.w);
                    pw[4] = f2bf(w1.x); pw[5] = f2bf(w1.y); pw[6] = f2bf(w1.z); pw[7] = f2bf(w1.w);
                } else {
#pragma unroll
                    for (int q = 0; q < 8; ++q) { pm[q] = 0; pw[q] = 0; }
                }
                int off = row * 512 + ((c * 16) ^ ((row & 7) << 4));
                *(u16x8*)((char*)Mb + off) = pm;
                *(u16x8*)((char*)Wb + off) = pw;
            }
        }
        __syncthreads();

        const int wr = w / 3, wc = w % 3;
        f32x4 acc[2][2];
#pragma unroll
        for (int i = 0; i < 2; ++i)
#pragma unroll
            for (int j = 0; j < 2; ++j) acc[i][j] = (f32x4)0.0f;
#pragma unroll
        for (int ks = 0; ks < 8; ++ks) {
            int kb = ks * 64 + (l >> 4) * 16;
            bf16x8 af[2], bfv[2];
#pragma unroll
            for (int mi = 0; mi < 2; ++mi) {
                int row = wr * 32 + mi * 16 + (l & 15);
                af[mi] = *(const bf16x8*)((char*)Mb + row * 512 + (kb ^ ((row & 7) << 4)));
            }
#pragma unroll
            for (int ni = 0; ni < 2; ++ni) {
                int row = wc * 32 + ni * 16 + (l & 15);
                bfv[ni] = *(const bf16x8*)((char*)Wb + row * 512 + (kb ^ ((row & 7) << 4)));
            }
#pragma unroll
            for (int mi = 0; mi < 2; ++mi)
#pragma unroll
                for (int ni = 0; ni < 2; ++ni)
                    acc[mi][ni] = __builtin_amdgcn_mfma_f32_16x16x32_bf16(
                        af[mi], bfv[ni], acc[mi][ni], 0, 0, 0);
        }
        __syncthreads();   // MFMA reads done; reuse region for P

#pragma unroll
        for (int mi = 0; mi < 2; ++mi)
#pragma unroll
            for (int ni = 0; ni < 2; ++ni)
#pragma unroll
                for (int j = 0; j < 4; ++j) {
                    int rowp = wr * 32 + mi * 16 + (l >> 4) * 4 + j;
                    int colp = wc * 32 + ni * 16 + (l & 15);
                    P[rowp * 97 + colp] = acc[mi][ni][j];
                }
        __syncthreads();

        if (tid < 96) {
            float m = -1e30f;
            for (int t = 0; t < Tq; ++t) m = fmaxf(m, P[t * 97 + tid]);
            float s = 0.f;
            for (int t = 0; t < Tq; ++t) s += __expf(P[t * 97 + tid] - m);
            mxs[tid] = m;
            rds[tid] = 1.f / s;
        }
        __syncthreads();

        // scatter (indices already in registers)
#pragma unroll
        for (int k = 0; k < 8; ++k) {
            int j = tid + k * 576;
            if (j < EAq) {
                float v = __expf(P[ed[k] * 97 + es[k]] - mxs[es[k]]) * rds[es[k]];
                atomicAdd(&A2f[((size_t)b * 96 + ed[k]) * KAq + et[k] * 96 + es[k]], v);
            }
        }
        if (tid < Tq * Oq) {
            int t = tid / Oq, o = tid % Oq;
            A2f[((size_t)b * 96 + Tq + o) * KAq + (Rq - 1) * 96 + t] =
                natt[(size_t)b * (Tq * Oq) + tid];
        }
        return;
    }

    // ======================= GEMM1 PATH (R10-proven 128x64, 576-thread staging) ======
    const int bid = blockIdx.x - 64;
    const int m0 = (bid / 96) * 128, n0 = (bid % 96) * 64;

    f32x4 acc[4][2];
#pragma unroll
    for (int i = 0; i < 4; ++i)
#pragma unroll
        for (int j = 0; j < 2; ++j) acc[i][j] = (f32x4)0.0f;

    char* const lbase0 = lds;
    char* const lbase1 = lds + 24576;

    auto stage = [&](char* base, int k0) {
#pragma unroll
        for (int i = 0; i < 3; ++i) {
            int idx = i * 576 + tid;            // wave-aligned: 576 = 9*64
            if (idx < 1536) {
                if (idx < 1024) {               // A: rows of Wt (128 x 64k)
                    int row = idx >> 3;
                    int csrc = (idx & 7) ^ (row & 7);
                    const unsigned short* g = Wt + (size_t)(m0 + row) * Dq + k0 + csrc * 8;
                    char* ld = base + (idx - l) * 16;
                    __builtin_amdgcn_global_load_lds((gu32*)g,
                        (lu32*)(unsigned int)(uintptr_t)ld, 16, 0, 0);
                } else {                        // B: rows of xb (64 x 64k)
                    int j = idx - 1024;
                    int row = j >> 3;
                    int csrc = (j & 7) ^ (row & 7);
                    const unsigned short* g = xb + (size_t)(n0 + row) * Dq + k0 + csrc * 8;
                    char* ld = base + 16384 + (j - l) * 16;
                    __builtin_amdgcn_global_load_lds((gu32*)g,
                        (lu32*)(unsigned int)(uintptr_t)ld, 16, 0, 0);
                }
            }
        }
    };

    stage(lbase0, 0);
    __syncthreads();

    const int wr = w >> 1, wc = w & 1;   // waves 0..3 compute; 4..8 stage-only
    int cur = 0;
    for (int t = 0; t < Dq / 64; ++t) {
        char* base = cur ? lbase1 : lbase0;
        if (t < Dq / 64 - 1) stage(cur ? lbase0 : lbase1, (t + 1) * 64);

        if (w < 4) {
            bf16x8 af[4][2], bfr[2][2];
#pragma unroll
            for (int ks = 0; ks < 2; ++ks) {
                int koff = ks * 64 + (l >> 4) * 16;
#pragma unroll
                for (int mi = 0; mi < 4; ++mi) {
                    int row = wr * 64 + mi * 16 + (l & 15);
                    af[mi][ks] = *(const bf16x8*)(base + row * 128 + (koff ^ ((row & 7) << 4)));
                }
#pragma unroll
                for (int ni = 0; ni < 2; ++ni) {
                    int row = wc * 32 + ni * 16 + (l & 15);
                    bfr[ni][ks] = *(const bf16x8*)(base + 16384 + row * 128 + (koff ^ ((row & 7) << 4)));
                }
            }
#pragma unroll
            for (int ks = 0; ks < 2; ++ks)
#pragma unroll
                for (int mi = 0; mi < 4; ++mi)
#pragma unroll
                    for (int ni = 0; ni < 2; ++ni)
                        acc[mi][ni] = __builtin_amdgcn_mfma_f32_16x16x32_bf16(
                            af[mi][ks], bfr[ni][ks], acc[mi][ni], 0, 0, 0);
        }
        __syncthreads();
        cur ^= 1;
    }

    if (w < 4) {
        // epilogue: per-wave [64][33] fp32 scratch -> row-contiguous bf16 stores
        float* epi = (float*)lds + w * 2112;
#pragma unroll
        for (int mi = 0; mi < 4; ++mi)
#pragma unroll
            for (int ni = 0; ni < 2; ++ni)
#pragma unroll
                for (int j = 0; j < 4; ++j) {
                    int row = mi * 16 + (l >> 4) * 4 + j;
                    int col = ni * 16 + (l & 15);
                    epi[row * 33 + col] = acc[mi][ni][j];
                }
        unsigned short* dst = xwT + (size_t)(m0 + wr * 64 + l) * NPq + n0 + wc * 32;
#pragma unroll
        for (int q = 0; q < 4; ++q) {
            u16x8 o;
#pragma unroll
            for (int e = 0; e < 8; ++e) o[e] = f2bf(epi[l * 33 + q * 8 + e]);
            *(u16x8*)(dst + q * 8) = o;
        }
    }
}

// ---------------- out[b*95+nl][h] = sum_k A2(fp32->bf16 lean-staged) * Ychunk + root + bias
__global__ __launch_bounds__(256) void k_gemm2(const float* __restrict__ A2f,
                                               const unsigned short* __restrict__ xwT,
                                               const float* __restrict__ bias,
                                               float* __restrict__ out) {
    __shared__ char lds[2][30720];      // per buf: A 96x96 bf16 (18432) + Y 64x96 bf16 (12288)
    const int tid = threadIdx.x;
    const int b = blockIdx.x;
    const int h0 = blockIdx.y * 64;
    const int w = tid >> 6, l = tid & 63;
    const int wr = w >> 1, wc = w & 1;

    f32x4 acc[3][2];
#pragma unroll
    for (int i = 0; i < 3; ++i)
#pragma unroll
        for (int j = 0; j < 2; ++j) acc[i][j] = (f32x4)0.0f;

    float4 a0[5], a1[5];                // lean staging regs, one set only
    auto loadA = [&](int r) {
#pragma unroll
        for (int i = 0; i < 5; ++i) {
            unsigned idx = tid + i * 256;
            if (idx < 1152) {
                unsigned row = idx / 12, u = idx - row * 12;
                const float4* s4 = (const float4*)(A2f + ((size_t)b * 96 + row) * KAq + r * 96 + u * 8);
                a0[i] = s4[0];
                a1[i] = s4[1];
            }
        }
    };
    auto writeA = [&](char* base) {
#pragma unroll
        for (int i = 0; i < 5; ++i) {
            unsigned idx = tid + i * 256;
            if (idx < 1152) {
                unsigned row = idx / 12, u = idx - row * 12;
                u16x8 pk;
                pk[0] = f2bf(a0[i].x); pk[1] = f2bf(a0[i].y);
                pk[2] = f2bf(a0[i].z); pk[3] = f2bf(a0[i].w);
                pk[4] = f2bf(a1[i].x); pk[5] = f2bf(a1[i].y);
                pk[6] = f2bf(a1[i].z); pk[7] = f2bf(a1[i].w);
                *(u16x8*)(base + row * 192 + ((u ^ (row & 3)) * 16)) = pk;
            }
        }
    };
    auto stageY = [&](int buf, int r) {
        char* base = &lds[buf][0];
#pragma unroll
        for (int i = 0; i < 3; ++i) {
            unsigned idx = tid + i * 256;
            unsigned row = idx / 12, u = idx - row * 12;
            unsigned usw = u ^ (row & 3);
            const unsigned short* g = xwT + (size_t)(r * 256 + h0 + row) * NPq + b * 96 + usw * 8;
            __builtin_amdgcn_global_load_lds((gu32*)g,
                (lu32*)(unsigned int)(uintptr_t)(base + 18432 + idx * 16), 16, 0, 0);
        }
    };

    loadA(0);
    writeA(&lds[0][0]);
    stageY(0, 0);
    __syncthreads();
    int cur = 0;
    for (int r = 0; r < 5; ++r) {
        char* base = &lds[cur][0];
        if (r < 4) { loadA(r + 1); stageY(cur ^ 1, r + 1); }   // issue loads early
        bf16x8 af[3], bfv[2];
#pragma unroll
        for (int ks = 0; ks < 3; ++ks) {
            int kb = ks * 64 + (l >> 4) * 16;
#pragma unroll
            for (int mi = 0; mi < 3; ++mi) {
                int row = wr * 48 + mi * 16 + (l & 15);
                af[mi] = *(const bf16x8*)(base + row * 192 + (kb ^ ((row & 3) << 4)));
            }
#pragma unroll
            for (int ni = 0; ni < 2; ++ni) {
                int row = wc * 32 + ni * 16 + (l & 15);
                bfv[ni] = *(const bf16x8*)(base + 18432 + row * 192 + (kb ^ ((row & 3) << 4)));
            }
#pragma unroll
            for (int mi = 0; mi < 3; ++mi)
#pragma unroll
                for (int ni = 0; ni < 2; ++ni)
                    acc[mi][ni] = __builtin_amdgcn_mfma_f32_16x16x32_bf16(
                        af[mi], bfv[ni], acc[mi][ni], 0, 0, 0);
        }
        if (r < 4) writeA(&lds[cur ^ 1][0]);                   // cvt+write late
        __syncthreads();
        cur ^= 1;
    }

#pragma unroll
    for (int mi = 0; mi < 3; ++mi) {
        int mrow = wr * 48 + mi * 16 + (l >> 4) * 4;
#pragma unroll
        for (int ni = 0; ni < 2; ++ni) {
            int n = h0 + wc * 32 + ni * 16 + (l & 15);
            float bv = bias[n];
            ushort4 rt = *(const ushort4*)(xwT + (size_t)(Rq * 256 + n) * NPq + b * 96 + mrow);
#pragma unroll
            for (int j = 0; j < 4; ++j) {
                int m = mrow + j;
                float rv = bf2f(j == 0 ? rt.x : j == 1 ? rt.y : j == 2 ? rt.z : rt.w);
                if (m < NPGq)
                    out[((size_t)b * NPGq + m) * Hq + n] = acc[mi][ni][j] + rv + bv;
            }
        }
    }
}

extern "C" void kernel_launch(void* const* d_in, const int* in_sizes, int n_in,
                              void* d_out, int out_size, void* d_ws, size_t ws_size,
                              hipStream_t stream) {
    (void)in_sizes; (void)n_in; (void)out_size; (void)ws_size;
    const float* M     = (const float*)d_in[0];
    const float* x     = (const float*)d_in[1];
    const float* natt  = (const float*)d_in[2];
    const float* Ws    = (const float*)d_in[3];
    const float* bases = (const float*)d_in[4];
    const float* comp  = (const float*)d_in[5];
    const float* rootw = (const float*)d_in[6];
    const float* bias  = (const float*)d_in[7];
    const int* esrc    = (const int*)d_in[8];
    const int* edst    = (const int*)d_in[9];
    const int* etype   = (const int*)d_in[10];
    float* out = (float*)d_out;
    char* ws = (char*)d_ws;

    unsigned short* Wt  = (unsigned short*)(ws + 0);          //    786,432 B
    float* A2f   = (float*)(ws + 786432);                     // 11,796,480 B
    unsigned short* xb  = (unsigned short*)(ws + 12582912);   //  3,145,728 B
    unsigned short* xwT = (unsigned short*)(ws + 15728640);   // 18,874,368 B (total ~34.6 MB)

    k_prep<<<dim3(3696), 256, 0, stream>>>(x, bases, comp, rootw, xb, Wt, A2f);
    k_main<<<dim3(64 + (KKq / 128) * (NPq / 64)), 576, 0, stream>>>(
        M, Ws, natt, esrc, edst, etype, A2f, Wt, xb, xwT);
    k_gemm2<<<dim3(Bq, Hq / 64), 256, 0, stream>>>(A2f, xwT, bias, out);
}

// Round 13
// 56.717 us; speedup vs baseline: 1.2640x; 1.0855x over previous
//
#include <hip/hip_runtime.h>
#include <cstddef>
#include <cstdint>

#define Bq 64
#define Tq 90
#define Oq 5
#define Dq 256
#define Hq 256
#define EAq 4096
#define Rq 5
#define NBq 8
#define NPGq 95
#define Nq 6080           // B*NPG real nodes
#define NPq 6144          // padded node space: 64 graphs x 96
#define EPBq 4546         // EA + T*O
#define Eq 290944         // B*EPB
#define KKq 1536          // (R+1)*D rows of WT / xwT
#define KAq 480           // A2 cols: 5 relations x 96

typedef __attribute__((ext_vector_type(8))) short bf16x8;
typedef __attribute__((ext_vector_type(8))) unsigned short u16x8;
typedef __attribute__((ext_vector_type(4))) float f32x4;
typedef __attribute__((address_space(1))) const unsigned int gu32;
typedef __attribute__((address_space(3))) unsigned int lu32;

__device__ __forceinline__ unsigned short f2bf(float f) {
    unsigned u = __float_as_uint(f);
    unsigned r = (u + 0x7FFF + ((u >> 16) & 1)) >> 16;
    return (unsigned short)r;
}
__device__ __forceinline__ float bf2f(unsigned short s) {
    return __uint_as_float(((unsigned)s) << 16);
}

// ---------------- prep: blocks 0..767: x->xb bf16; 768..815: Wt compute
__global__ __launch_bounds__(256) void k_prep(const float* __restrict__ x,
                                              const float* __restrict__ bases,
                                              const float* __restrict__ comp,
                                              const float* __restrict__ rootw,
                                              unsigned short* __restrict__ xb,
                                              unsigned short* __restrict__ Wt) {
    __shared__ float Ld[32][257];
    int blk = blockIdx.x;
    if (blk < 768) {
        unsigned i = blk * 256 + threadIdx.x;  // over NPq*32 chunks of 8
        unsigned np = i >> 5, c = i & 31;
        unsigned s = np % 96;
        u16x8 pk;
        if (s == 95) {
#pragma unroll
            for (int q = 0; q < 8; ++q) pk[q] = 0;
        } else {
            unsigned node = np - np / 96;
            const float4* xs = (const float4*)(x + (size_t)node * Dq + c * 8);
            float4 a = xs[0], b2 = xs[1];
            pk[0] = f2bf(a.x);  pk[1] = f2bf(a.y);  pk[2] = f2bf(a.z);  pk[3] = f2bf(a.w);
            pk[4] = f2bf(b2.x); pk[5] = f2bf(b2.y); pk[6] = f2bf(b2.z); pk[7] = f2bf(b2.w);
        }
        *(u16x8*)(xb + (size_t)np * Dq + c * 8) = pk;
        return;
    }
    // Wt: WT[kk][d] bf16; kk=r*256+h or 1280+h (root)
    int wblk = blk - 768;             // 0..47
    int rs = wblk >> 3;               // 0..5
    int d0 = (wblk & 7) * 32;
    int t = threadIdx.x;              // h
    float cmp[NBq];
    if (rs < Rq)
#pragma unroll
        for (int nb = 0; nb < NBq; ++nb) cmp[nb] = comp[rs * NBq + nb];
    for (int dl = 0; dl < 32; ++dl) {
        int d = d0 + dl;
        float v;
        if (rs < Rq) {
            v = 0.f;
#pragma unroll
            for (int nb = 0; nb < NBq; ++nb)
                v += cmp[nb] * bases[((size_t)nb * Dq + d) * Hq + t];
        } else {
            v = rootw[(size_t)d * Hq + t];
        }
        Ld[dl][t] = v;
    }
    __syncthreads();
    int c = t & 31, hg = t >> 5;
    for (int hh = 0; hh < 32; ++hh) {
        int h = hg * 32 + hh;
        Wt[(size_t)(rs * 256 + h) * Dq + d0 + c] = f2bf(Ld[c][h]);
    }
}

// ---------------- fused main: blocks 0..63 = attn(graph b) -> A2b (LDS-accumulated);
//                  blocks 64..1215 = gemm1 tile
__global__ __launch_bounds__(576) void k_main(const float* __restrict__ M,
                                              const float* __restrict__ Ws,
                                              const float* __restrict__ natt,
                                              const int* __restrict__ esrc,
                                              const int* __restrict__ edst,
                                              const int* __restrict__ etype,
                                              unsigned short* __restrict__ A2b,
                                              const unsigned short* __restrict__ Wt,
                                              const unsigned short* __restrict__ xb,
                                              unsigned short* __restrict__ xwT) {
    __shared__ __attribute__((aligned(16))) char lds[99072];
    const int tid = threadIdx.x;
    const int w = tid >> 6, l = tid & 63;

    if (blockIdx.x < 64) {
        // ======================= ATTN PATH (LDS-scatter) =============================
        unsigned short* Mb = (unsigned short*)lds;           // [96][256] bf16 swz (48KB)
        unsigned short* Wb = (unsigned short*)(lds + 49152); // [96][256] bf16 swz (48KB)
        float* P   = (float*)lds;                            // [96][97] fp32 (reuses Mb)
        float* Acc = (float*)(lds + 49152);                  // [96][96] fp32 (reuses Wb)
        float* mxs = (float*)(lds + 98304);                  // [96]
        float* rds = (float*)(lds + 98688);                  // [96]
        const int b = blockIdx.x;

        // hoist edge indices + tag value: loads issue now, consumed much later
        int es[8], ed[8], et[8];
#pragma unroll
        for (int k = 0; k < 8; ++k) {
            int j = tid + k * 576;
            if (j < EAq) {
                es[k] = esrc[(size_t)b * EAq + j];
                ed[k] = edst[(size_t)b * EAq + j];
                et[k] = etype[(size_t)b * EAq + j];
            }
        }
        float tagv = (tid < Tq * Oq) ? natt[(size_t)b * (Tq * Oq) + tid] : 0.f;

#pragma unroll
        for (int i = 0; i < 6; ++i) {
            int idx = tid + i * 576;            // 0..3455, want 0..3071
            if (idx < 3072) {
                int row = idx >> 5, c = idx & 31;
                u16x8 pm, pw;
                if (row < Tq) {
                    const float4* ms = (const float4*)(M + ((size_t)b * Tq + row) * Dq + c * 8);
                    float4 a0 = ms[0], a1 = ms[1];
                    pm[0] = f2bf(a0.x); pm[1] = f2bf(a0.y); pm[2] = f2bf(a0.z); pm[3] = f2bf(a0.w);
                    pm[4] = f2bf(a1.x); pm[5] = f2bf(a1.y); pm[6] = f2bf(a1.z); pm[7] = f2bf(a1.w);
                    const float4* ws = (const float4*)(Ws + (size_t)row * Dq + c * 8);
                    float4 w0 = ws[0], w1 = ws[1];
                    pw[0] = f2bf(w0.x); pw[1] = f2bf(w0.y); pw[2] = f2bf(w0.z); pw[3] = f2bf(w0.w);
                    pw[4] = f2bf(w1.x); pw[5] = f2bf(w1.y); pw[6] = f2bf(w1.z); pw[7] = f2bf(w1.w);
                } else {
#pragma unroll
                    for (int q = 0; q < 8; ++q) { pm[q] = 0; pw[q] = 0; }
                }
                int off = row * 512 + ((c * 16) ^ ((row & 7) << 4));
                *(u16x8*)((char*)Mb + off) = pm;
                *(u16x8*)((char*)Wb + off) = pw;
            }
        }
        __syncthreads();

        const int wr = w / 3, wc = w % 3;
        f32x4 acc[2][2];
#pragma unroll
        for (int i = 0; i < 2; ++i)
#pragma unroll
            for (int j = 0; j < 2; ++j) acc[i][j] = (f32x4)0.0f;
#pragma unroll
        for (int ks = 0; ks < 8; ++ks) {
            int kb = ks * 64 + (l >> 4) * 16;
            bf16x8 af[2], bfv[2];
#pragma unroll
            for (int mi = 0; mi < 2; ++mi) {
                int row = wr * 32 + mi * 16 + (l & 15);
                af[mi] = *(const bf16x8*)((char*)Mb + row * 512 + (kb ^ ((row & 7) << 4)));
            }
#pragma unroll
            for (int ni = 0; ni < 2; ++ni) {
                int row = wc * 32 + ni * 16 + (l & 15);
                bfv[ni] = *(const bf16x8*)((char*)Wb + row * 512 + (kb ^ ((row & 7) << 4)));
            }
#pragma unroll
            for (int mi = 0; mi < 2; ++mi)
#pragma unroll
                for (int ni = 0; ni < 2; ++ni)
                    acc[mi][ni] = __builtin_amdgcn_mfma_f32_16x16x32_bf16(
                        af[mi], bfv[ni], acc[mi][ni], 0, 0, 0);
        }
        __syncthreads();   // MFMA reads done; Mb->P, Wb->Acc reuse now legal

#pragma unroll
        for (int mi = 0; mi < 2; ++mi)
#pragma unroll
            for (int ni = 0; ni < 2; ++ni)
#pragma unroll
                for (int j = 0; j < 4; ++j) {
                    int rowp = wr * 32 + mi * 16 + (l >> 4) * 4 + j;
                    int colp = wc * 32 + ni * 16 + (l & 15);
                    P[rowp * 97 + colp] = acc[mi][ni][j];
                }
        __syncthreads();

        if (tid < 96) {
            float m = -1e30f;
            for (int t = 0; t < Tq; ++t) m = fmaxf(m, P[t * 97 + tid]);
            float s = 0.f;
            for (int t = 0; t < Tq; ++t) s += __expf(P[t * 97 + tid] - m);
            mxs[tid] = m;
            rds[tid] = 1.f / s;
        }
        __syncthreads();

        // per-edge normalized value (P + stats stay resident in LDS)
        float v[8];
#pragma unroll
        for (int k = 0; k < 8; ++k) {
            int j = tid + k * 576;
            if (j < EAq)
                v[k] = __expf(P[ed[k] * 97 + es[k]] - mxs[es[k]]) * rds[es[k]];
        }

        // per-relation LDS accumulate -> bf16 bulk store (no global atomics)
        for (int r = 0; r < Rq; ++r) {
#pragma unroll
            for (int i = 0; i < 4; ++i)                      // zero 9216 floats
                ((float4*)Acc)[tid + i * 576] = make_float4(0.f, 0.f, 0.f, 0.f);
            __syncthreads();
#pragma unroll
            for (int k = 0; k < 8; ++k) {
                int j = tid + k * 576;
                if (j < EAq && et[k] == r)
                    atomicAdd(&Acc[ed[k] * 96 + es[k]], v[k]);
            }
            if (r == Rq - 1 && tid < Tq * Oq) {              // tag rows 90..94: unique slots
                int t = tid / Oq, o = tid % Oq;
                Acc[(Tq + o) * 96 + t] = tagv;
            }
            __syncthreads();
#pragma unroll
            for (int i = 0; i < 2; ++i) {                    // store 96x96 bf16
                int c0 = tid + i * 576;                      // 0..1151
                const float* src = Acc + (c0 / 12) * 96 + (c0 % 12) * 8;
                u16x8 pk;
#pragma unroll
                for (int q = 0; q < 8; ++q) pk[q] = f2bf(src[q]);
                *(u16x8*)(A2b + ((size_t)b * 96 + c0 / 12) * KAq + r * 96 + (c0 % 12) * 8) = pk;
            }
            __syncthreads();                                 // protect Acc before next zero
        }
        return;
    }

    // ======================= GEMM1 PATH (R12-proven 128x64, 576-thread staging) ======
    const int bid = blockIdx.x - 64;
    const int m0 = (bid / 96) * 128, n0 = (bid % 96) * 64;

    f32x4 acc[4][2];
#pragma unroll
    for (int i = 0; i < 4; ++i)
#pragma unroll
        for (int j = 0; j < 2; ++j) acc[i][j] = (f32x4)0.0f;

    char* const lbase0 = lds;
    char* const lbase1 = lds + 24576;

    auto stage = [&](char* base, int k0) {
#pragma unroll
        for (int i = 0; i < 3; ++i) {
            int idx = i * 576 + tid;            // wave-aligned: 576 = 9*64
            if (idx < 1536) {
                if (idx < 1024) {               // A: rows of Wt (128 x 64k)
                    int row = idx >> 3;
                    int csrc = (idx & 7) ^ (row & 7);
                    const unsigned short* g = Wt + (size_t)(m0 + row) * Dq + k0 + csrc * 8;
                    char* ld = base + (idx - l) * 16;
                    __builtin_amdgcn_global_load_lds((gu32*)g,
                        (lu32*)(unsigned int)(uintptr_t)ld, 16, 0, 0);
                } else {                        // B: rows of xb (64 x 64k)
                    int j = idx - 1024;
                    int row = j >> 3;
                    int csrc = (j & 7) ^ (row & 7);
                    const unsigned short* g = xb + (size_t)(n0 + row) * Dq + k0 + csrc * 8;
                    char* ld = base + 16384 + (j - l) * 16;
                    __builtin_amdgcn_global_load_lds((gu32*)g,
                        (lu32*)(unsigned int)(uintptr_t)ld, 16, 0, 0);
                }
            }
        }
    };

    stage(lbase0, 0);
    __syncthreads();

    const int wr = w >> 1, wc = w & 1;   // waves 0..3 compute; 4..8 stage-only
    int cur = 0;
    for (int t = 0; t < Dq / 64; ++t) {
        char* base = cur ? lbase1 : lbase0;
        if (t < Dq / 64 - 1) stage(cur ? lbase0 : lbase1, (t + 1) * 64);

        if (w < 4) {
            bf16x8 af[4][2], bfr[2][2];
#pragma unroll
            for (int ks = 0; ks < 2; ++ks) {
                int koff = ks * 64 + (l >> 4) * 16;
#pragma unroll
                for (int mi = 0; mi < 4; ++mi) {
                    int row = wr * 64 + mi * 16 + (l & 15);
                    af[mi][ks] = *(const bf16x8*)(base + row * 128 + (koff ^ ((row & 7) << 4)));
                }
#pragma unroll
                for (int ni = 0; ni < 2; ++ni) {
                    int row = wc * 32 + ni * 16 + (l & 15);
                    bfr[ni][ks] = *(const bf16x8*)(base + 16384 + row * 128 + (koff ^ ((row & 7) << 4)));
                }
            }
#pragma unroll
            for (int ks = 0; ks < 2; ++ks)
#pragma unroll
                for (int mi = 0; mi < 4; ++mi)
#pragma unroll
                    for (int ni = 0; ni < 2; ++ni)
                        acc[mi][ni] = __builtin_amdgcn_mfma_f32_16x16x32_bf16(
                            af[mi][ks], bfr[ni][ks], acc[mi][ni], 0, 0, 0);
        }
        __syncthreads();
        cur ^= 1;
    }

    if (w < 4) {
        // epilogue: per-wave [64][33] fp32 scratch -> row-contiguous bf16 stores
        float* epi = (float*)lds + w * 2112;
#pragma unroll
        for (int mi = 0; mi < 4; ++mi)
#pragma unroll
            for (int ni = 0; ni < 2; ++ni)
#pragma unroll
                for (int j = 0; j < 4; ++j) {
                    int row = mi * 16 + (l >> 4) * 4 + j;
                    int col = ni * 16 + (l & 15);
                    epi[row * 33 + col] = acc[mi][ni][j];
                }
        unsigned short* dst = xwT + (size_t)(m0 + wr * 64 + l) * NPq + n0 + wc * 32;
#pragma unroll
        for (int q = 0; q < 4; ++q) {
            u16x8 o;
#pragma unroll
            for (int e = 0; e < 8; ++e) o[e] = f2bf(epi[l * 33 + q * 8 + e]);
            *(u16x8*)(dst + q * 8) = o;
        }
    }
}

// ---------------- out[b*95+nl][h] = sum_k A2b[b][nl][k] * Ychunk + root + bias  (R8-proven)
__global__ __launch_bounds__(256) void k_gemm2(const unsigned short* __restrict__ A2b,
                                               const unsigned short* __restrict__ xwT,
                                               const float* __restrict__ bias,
                                               float* __restrict__ out) {
    __shared__ char lds[2][30720];      // per buf: A 96x96 bf16 (18432) + Y 64x96 bf16 (12288)
    const int tid = threadIdx.x;
    const int b = blockIdx.x;
    const int h0 = blockIdx.y * 64;
    const int w = tid >> 6, l = tid & 63;
    const int wr = w >> 1, wc = w & 1;

    f32x4 acc[3][2];
#pragma unroll
    for (int i = 0; i < 3; ++i)
#pragma unroll
        for (int j = 0; j < 2; ++j) acc[i][j] = (f32x4)0.0f;

    auto stage = [&](int buf, int r) {
        char* base = &lds[buf][0];
#pragma unroll
        for (int i = 0; i < 5; ++i) {
            unsigned idx = tid + i * 256;
            if (idx < 1152) {
                unsigned row = idx / 12, u = idx - row * 12;
                unsigned usw = u ^ (row & 3);
                const unsigned short* g = A2b + ((size_t)b * 96 + row) * KAq + r * 96 + usw * 8;
                __builtin_amdgcn_global_load_lds((gu32*)g,
                    (lu32*)(unsigned int)(uintptr_t)(base + idx * 16), 16, 0, 0);
            }
        }
#pragma unroll
        for (int i = 0; i < 3; ++i) {
            unsigned idx = tid + i * 256;
            unsigned row = idx / 12, u = idx - row * 12;
            unsigned usw = u ^ (row & 3);
            const unsigned short* g = xwT + (size_t)(r * 256 + h0 + row) * NPq + b * 96 + usw * 8;
            __builtin_amdgcn_global_load_lds((gu32*)g,
                (lu32*)(unsigned int)(uintptr_t)(base + 18432 + idx * 16), 16, 0, 0);
        }
    };

    stage(0, 0);
    __syncthreads();
    int cur = 0;
    for (int r = 0; r < 5; ++r) {
        char* base = &lds[cur][0];
        if (r < 4) stage(cur ^ 1, r + 1);
        bf16x8 af[3], bfv[2];
#pragma unroll
        for (int ks = 0; ks < 3; ++ks) {
            int kb = ks * 64 + (l >> 4) * 16;
#pragma unroll
            for (int mi = 0; mi < 3; ++mi) {
                int row = wr * 48 + mi * 16 + (l & 15);
                af[mi] = *(const bf16x8*)(base + row * 192 + (kb ^ ((row & 3) << 4)));
            }
#pragma unroll
            for (int ni = 0; ni < 2; ++ni) {
                int row = wc * 32 + ni * 16 + (l & 15);
                bfv[ni] = *(const bf16x8*)(base + 18432 + row * 192 + (kb ^ ((row & 3) << 4)));
            }
#pragma unroll
            for (int mi = 0; mi < 3; ++mi)
#pragma unroll
                for (int ni = 0; ni < 2; ++ni)
                    acc[mi][ni] = __builtin_amdgcn_mfma_f32_16x16x32_bf16(
                        af[mi], bfv[ni], acc[mi][ni], 0, 0, 0);
        }
        __syncthreads();
        cur ^= 1;
    }

#pragma unroll
    for (int mi = 0; mi < 3; ++mi) {
        int mrow = wr * 48 + mi * 16 + (l >> 4) * 4;
#pragma unroll
        for (int ni = 0; ni < 2; ++ni) {
            int n = h0 + wc * 32 + ni * 16 + (l & 15);
            float bv = bias[n];
            ushort4 rt = *(const ushort4*)(xwT + (size_t)(Rq * 256 + n) * NPq + b * 96 + mrow);
#pragma unroll
            for (int j = 0; j < 4; ++j) {
                int m = mrow + j;
                float rv = bf2f(j == 0 ? rt.x : j == 1 ? rt.y : j == 2 ? rt.z : rt.w);
                if (m < NPGq)
                    out[((size_t)b * NPGq + m) * Hq + n] = acc[mi][ni][j] + rv + bv;
            }
        }
    }
}

extern "C" void kernel_launch(void* const* d_in, const int* in_sizes, int n_in,
                              void* d_out, int out_size, void* d_ws, size_t ws_size,
                              hipStream_t stream) {
    (void)in_sizes; (void)n_in; (void)out_size; (void)ws_size;
    const float* M     = (const float*)d_in[0];
    const float* x     = (const float*)d_in[1];
    const float* natt  = (const float*)d_in[2];
    const float* Ws    = (const float*)d_in[3];
    const float* bases = (const float*)d_in[4];
    const float* comp  = (const float*)d_in[5];
    const float* rootw = (const float*)d_in[6];
    const float* bias  = (const float*)d_in[7];
    const int* esrc    = (const int*)d_in[8];
    const int* edst    = (const int*)d_in[9];
    const int* etype   = (const int*)d_in[10];
    float* out = (float*)d_out;
    char* ws = (char*)d_ws;

    unsigned short* Wt  = (unsigned short*)(ws + 0);          //    786,432 B
    unsigned short* A2b = (unsigned short*)(ws + 786432);     //  5,898,240 B
    unsigned short* xb  = (unsigned short*)(ws + 6684672);    //  3,145,728 B
    unsigned short* xwT = (unsigned short*)(ws + 9830400);    // 18,874,368 B (total ~28.7 MB)

    k_prep<<<dim3(816), 256, 0, stream>>>(x, bases, comp, rootw, xb, Wt);
    k_main<<<dim3(64 + (KKq / 128) * (NPq / 64)), 576, 0, stream>>>(
        M, Ws, natt, esrc, edst, etype, A2b, Wt, xb, xwT);
    k_gemm2<<<dim3(Bq, Hq / 64), 256, 0, stream>>>(A2b, xwT, bias, out);
}

// Round 14
// 41.060 us; speedup vs baseline: 1.7460x; 1.3813x over previous
//
#include <hip/hip_runtime.h>
#include <cstddef>
#include <cstdint>

#define Bq 64
#define Tq 90
#define Oq 5
#define Dq 256
#define Hq 256
#define EAq 4096
#define Rq 5
#define NBq 8
#define NPGq 95
#define Nq 6080           // B*NPG real nodes
#define NPq 6144          // padded node space: 64 graphs x 96
#define EPBq 4546         // EA + T*O
#define Eq 290944         // B*EPB
#define KAq 480           // A2 cols: 5 relations x 96

typedef __attribute__((ext_vector_type(8))) short bf16x8;
typedef __attribute__((ext_vector_type(8))) unsigned short u16x8;
typedef __attribute__((ext_vector_type(4))) float f32x4;
typedef __attribute__((address_space(1))) const unsigned int gu32;
typedef __attribute__((address_space(3))) unsigned int lu32;

__device__ __forceinline__ unsigned short f2bf(float f) {
    unsigned u = __float_as_uint(f);
    unsigned r = (u + 0x7FFF + ((u >> 16) & 1)) >> 16;
    return (unsigned short)r;
}
__device__ __forceinline__ float bf2f(unsigned short s) {
    return __uint_as_float(((unsigned)s) << 16);
}

// ---------------- L1: blocks 0..63 attn -> A2b; 64..405 x->xb; 406..453 Wt
__global__ __launch_bounds__(576) void k_pa(const float* __restrict__ M,
                                            const float* __restrict__ Ws,
                                            const float* __restrict__ natt,
                                            const int* __restrict__ esrc,
                                            const int* __restrict__ edst,
                                            const int* __restrict__ etype,
                                            const float* __restrict__ x,
                                            const float* __restrict__ bases,
                                            const float* __restrict__ comp,
                                            const float* __restrict__ rootw,
                                            unsigned short* __restrict__ A2b,
                                            unsigned short* __restrict__ xb,
                                            unsigned short* __restrict__ Wt) {
    __shared__ __attribute__((aligned(16))) char lds[99072];
    const int tid = threadIdx.x;
    const int w = tid >> 6, l = tid & 63;
    const int blk = blockIdx.x;

    if (blk >= 64 && blk < 406) {
        // ---- xb conversion (x fp32 -> padded bf16 rows) ----
        unsigned i = (unsigned)(blk - 64) * 576 + tid;
        if (i < NPq * 32) {
            unsigned np = i >> 5, c = i & 31;
            unsigned s = np % 96;
            u16x8 pk;
            if (s == 95) {
#pragma unroll
                for (int q = 0; q < 8; ++q) pk[q] = 0;
            } else {
                unsigned node = np - np / 96;
                const float4* xs = (const float4*)(x + (size_t)node * Dq + c * 8);
                float4 a = xs[0], b2 = xs[1];
                pk[0] = f2bf(a.x);  pk[1] = f2bf(a.y);  pk[2] = f2bf(a.z);  pk[3] = f2bf(a.w);
                pk[4] = f2bf(b2.x); pk[5] = f2bf(b2.y); pk[6] = f2bf(b2.z); pk[7] = f2bf(b2.w);
            }
            *(u16x8*)(xb + (size_t)np * Dq + c * 8) = pk;
        }
        return;
    }
    if (blk >= 406) {
        // ---- Wt compute (256 active threads; barrier hoisted to all-thread level) ----
        float* Ld = (float*)lds;          // [32][257]
        int wblk = blk - 406;             // 0..47
        int rs = wblk >> 3;               // 0..5
        int d0 = (wblk & 7) * 32;
        int t = tid;
        if (t < 256) {
            float cmp[NBq];
            if (rs < Rq)
#pragma unroll
                for (int nb = 0; nb < NBq; ++nb) cmp[nb] = comp[rs * NBq + nb];
            for (int dl = 0; dl < 32; ++dl) {
                int d = d0 + dl;
                float v;
                if (rs < Rq) {
                    v = 0.f;
#pragma unroll
                    for (int nb = 0; nb < NBq; ++nb)
                        v += cmp[nb] * bases[((size_t)nb * Dq + d) * Hq + t];
                } else {
                    v = rootw[(size_t)d * Hq + t];
                }
                Ld[dl * 257 + t] = v;
            }
        }
        __syncthreads();
        if (t < 256) {
            int c = t & 31, hg = t >> 5;
            for (int hh = 0; hh < 32; ++hh) {
                int h = hg * 32 + hh;
                Wt[(size_t)(rs * 256 + h) * Dq + d0 + c] = f2bf(Ld[c * 257 + h]);
            }
        }
        return;
    }

    // ======================= ATTN PATH (R13-proven LDS-scatter) ======================
    unsigned short* Mb = (unsigned short*)lds;           // [96][256] bf16 swz (48KB)
    unsigned short* Wb = (unsigned short*)(lds + 49152); // [96][256] bf16 swz (48KB)
    float* P   = (float*)lds;                            // [96][97] fp32 (reuses Mb)
    float* Acc = (float*)(lds + 49152);                  // [96][96] fp32 (reuses Wb)
    float* mxs = (float*)(lds + 98304);                  // [96]
    float* rds = (float*)(lds + 98688);                  // [96]
    const int b = blk;

    int es[8], ed[8], et[8];
#pragma unroll
    for (int k = 0; k < 8; ++k) {
        int j = tid + k * 576;
        if (j < EAq) {
            es[k] = esrc[(size_t)b * EAq + j];
            ed[k] = edst[(size_t)b * EAq + j];
            et[k] = etype[(size_t)b * EAq + j];
        }
    }
    float tagv = (tid < Tq * Oq) ? natt[(size_t)b * (Tq * Oq) + tid] : 0.f;

#pragma unroll
    for (int i = 0; i < 6; ++i) {
        int idx = tid + i * 576;            // 0..3455, want 0..3071
        if (idx < 3072) {
            int row = idx >> 5, c = idx & 31;
            u16x8 pm, pw;
            if (row < Tq) {
                const float4* ms = (const float4*)(M + ((size_t)b * Tq + row) * Dq + c * 8);
                float4 a0 = ms[0], a1 = ms[1];
                pm[0] = f2bf(a0.x); pm[1] = f2bf(a0.y); pm[2] = f2bf(a0.z); pm[3] = f2bf(a0.w);
                pm[4] = f2bf(a1.x); pm[5] = f2bf(a1.y); pm[6] = f2bf(a1.z); pm[7] = f2bf(a1.w);
                const float4* ws = (const float4*)(Ws + (size_t)row * Dq + c * 8);
                float4 w0 = ws[0], w1 = ws[1];
                pw[0] = f2bf(w0.x); pw[1] = f2bf(w0.y); pw[2] = f2bf(w0.z); pw[3] = f2bf(w0.w);
                pw[4] = f2bf(w1.x); pw[5] = f2bf(w1.y); pw[6] = f2bf(w1.z); pw[7] = f2bf(w1.w);
            } else {
#pragma unroll
                for (int q = 0; q < 8; ++q) { pm[q] = 0; pw[q] = 0; }
            }
            int off = row * 512 + ((c * 16) ^ ((row & 7) << 4));
            *(u16x8*)((char*)Mb + off) = pm;
            *(u16x8*)((char*)Wb + off) = pw;
        }
    }
    __syncthreads();

    const int wr = w / 3, wc = w % 3;
    f32x4 acc[2][2];
#pragma unroll
    for (int i = 0; i < 2; ++i)
#pragma unroll
        for (int j = 0; j < 2; ++j) acc[i][j] = (f32x4)0.0f;
#pragma unroll
    for (int ks = 0; ks < 8; ++ks) {
        int kb = ks * 64 + (l >> 4) * 16;
        bf16x8 af[2], bfv[2];
#pragma unroll
        for (int mi = 0; mi < 2; ++mi) {
            int row = wr * 32 + mi * 16 + (l & 15);
            af[mi] = *(const bf16x8*)((char*)Mb + row * 512 + (kb ^ ((row & 7) << 4)));
        }
#pragma unroll
        for (int ni = 0; ni < 2; ++ni) {
            int row = wc * 32 + ni * 16 + (l & 15);
            bfv[ni] = *(const bf16x8*)((char*)Wb + row * 512 + (kb ^ ((row & 7) << 4)));
        }
#pragma unroll
        for (int mi = 0; mi < 2; ++mi)
#pragma unroll
            for (int ni = 0; ni < 2; ++ni)
                acc[mi][ni] = __builtin_amdgcn_mfma_f32_16x16x32_bf16(
                    af[mi], bfv[ni], acc[mi][ni], 0, 0, 0);
    }
    __syncthreads();   // MFMA reads done; Mb->P, Wb->Acc reuse now legal

#pragma unroll
    for (int mi = 0; mi < 2; ++mi)
#pragma unroll
        for (int ni = 0; ni < 2; ++ni)
#pragma unroll
            for (int j = 0; j < 4; ++j) {
                int rowp = wr * 32 + mi * 16 + (l >> 4) * 4 + j;
                int colp = wc * 32 + ni * 16 + (l & 15);
                P[rowp * 97 + colp] = acc[mi][ni][j];
            }
    __syncthreads();

    if (tid < 96) {
        float m = -1e30f;
        for (int t = 0; t < Tq; ++t) m = fmaxf(m, P[t * 97 + tid]);
        float s = 0.f;
        for (int t = 0; t < Tq; ++t) s += __expf(P[t * 97 + tid] - m);
        mxs[tid] = m;
        rds[tid] = 1.f / s;
    }
    __syncthreads();

    float v[8];
#pragma unroll
    for (int k = 0; k < 8; ++k) {
        int j = tid + k * 576;
        if (j < EAq)
            v[k] = __expf(P[ed[k] * 97 + es[k]] - mxs[es[k]]) * rds[es[k]];
    }

    for (int r = 0; r < Rq; ++r) {
#pragma unroll
        for (int i = 0; i < 4; ++i)
            ((float4*)Acc)[tid + i * 576] = make_float4(0.f, 0.f, 0.f, 0.f);
        __syncthreads();
#pragma unroll
        for (int k = 0; k < 8; ++k) {
            int j = tid + k * 576;
            if (j < EAq && et[k] == r)
                atomicAdd(&Acc[ed[k] * 96 + es[k]], v[k]);
        }
        if (r == Rq - 1 && tid < Tq * Oq) {
            int t = tid / Oq, o = tid % Oq;
            Acc[(Tq + o) * 96 + t] = tagv;
        }
        __syncthreads();
#pragma unroll
        for (int i = 0; i < 2; ++i) {
            int c0 = tid + i * 576;                      // 0..1151
            const float* src = Acc + (c0 / 12) * 96 + (c0 % 12) * 8;
            u16x8 pk;
#pragma unroll
            for (int q = 0; q < 8; ++q) pk[q] = f2bf(src[q]);
            *(u16x8*)(A2b + ((size_t)b * 96 + c0 / 12) * KAq + r * 96 + (c0 % 12) * 8) = pk;
        }
        __syncthreads();
    }
}

// ---------------- L2: fused per-graph back-half (R11-proven + dbuf W + bf16 A2 glds)
// block (hc, b): acc[96 nl][64 h] = sum_r A2_r @ (W_r-chunk @ X_b^T)^T + root + bias
__global__ __launch_bounds__(512) void k_gemm3(const unsigned short* __restrict__ A2b,
                                               const unsigned short* __restrict__ Wt,
                                               const unsigned short* __restrict__ xb,
                                               const float* __restrict__ bias,
                                               float* __restrict__ out) {
    __shared__ __attribute__((aligned(16))) char lds[145408];
    char* const Xs  = lds;               // [96][512B]  swizzled bf16   48KB
    char* const Wl0 = lds + 49152;       // [64][512B]  swizzled bf16   32KB
    char* const Wl1 = lds + 81920;       // [64][512B]  swizzled bf16   32KB
    char* const Ztl = lds + 114688;      // [64][192B]  swizzled bf16   12KB
    char* const A2l = lds + 126976;      // [96][192B]  swizzled bf16   18KB
    const int hc = blockIdx.x;           // 0..3
    const int b  = blockIdx.y;           // 0..63
    const int tid = threadIdx.x;
    const int w = tid >> 6, l = tid & 63;
    const int wrz = w >> 1, wcz = w & 1;   // gemm-Z grid: 4(h) x 2(s)
    const int wrn = w >> 2, wcn = w & 3;   // gemm-out grid: 2(nl) x 4(h)

    // stage X_b once (3072 chunks, 6 iters)
#pragma unroll
    for (int i = 0; i < 6; ++i) {
        int idx = i * 512 + tid;
        int row = idx >> 5, c = idx & 31;
        const unsigned short* g = xb + (size_t)(b * 96 + row) * Dq + (c ^ (row & 7)) * 8;
        __builtin_amdgcn_global_load_lds((gu32*)g,
            (lu32*)(unsigned int)(uintptr_t)(Xs + idx * 16), 16, 0, 0);
    }

    f32x4 acc[3];
#pragma unroll
    for (int i = 0; i < 3; ++i) acc[i] = (f32x4)0.0f;

    auto stageW = [&](char* Wbuf, int slice) {   // W rows slice*256? no: kkbase formula below
        int kkbase = slice * 256 + hc * 64;      // slice 0..4 relations, 5 = root (5*256=1280 ✓)
#pragma unroll
        for (int i = 0; i < 4; ++i) {
            int idx = i * 512 + tid;
            int hrow = idx >> 5, c = idx & 31;
            const unsigned short* g = Wt + (size_t)(kkbase + hrow) * Dq + (c ^ (hrow & 7)) * 8;
            __builtin_amdgcn_global_load_lds((gu32*)g,
                (lu32*)(unsigned int)(uintptr_t)(Wbuf + idx * 16), 16, 0, 0);
        }
    };
    auto stageA2 = [&](int r) {                  // 1152 chunks, pre-swizzled source
#pragma unroll
        for (int i = 0; i < 3; ++i) {
            int idx = i * 512 + tid;
            if (idx < 1152) {
                int row = idx / 12, u = idx - row * 12;
                int usw = u ^ (row & 3);
                const unsigned short* g = A2b + ((size_t)b * 96 + row) * KAq + r * 96 + usw * 8;
                __builtin_amdgcn_global_load_lds((gu32*)g,
                    (lu32*)(unsigned int)(uintptr_t)(A2l + idx * 16), 16, 0, 0);
            }
        }
    };
    auto gemmZ = [&](char* Wbuf, f32x4 (&zacc)[3]) {   // zacc[ni] over (16h x 48s)
#pragma unroll
        for (int i = 0; i < 3; ++i) zacc[i] = (f32x4)0.0f;
#pragma unroll
        for (int ks = 0; ks < 8; ++ks) {
            int kb = ks * 64 + (l >> 4) * 16;
            int hl = wrz * 16 + (l & 15);
            bf16x8 af = *(const bf16x8*)(Wbuf + hl * 512 + (kb ^ ((hl & 7) << 4)));
#pragma unroll
            for (int ni = 0; ni < 3; ++ni) {
                int s = wcz * 48 + ni * 16 + (l & 15);
                bf16x8 xv = *(const bf16x8*)(Xs + s * 512 + (kb ^ ((s & 7) << 4)));
                zacc[ni] = __builtin_amdgcn_mfma_f32_16x16x32_bf16(af, xv, zacc[ni], 0, 0, 0);
            }
        }
    };
    auto writeZt = [&](f32x4 (&zacc)[3]) {
#pragma unroll
        for (int ni = 0; ni < 3; ++ni)
#pragma unroll
            for (int j = 0; j < 4; ++j) {
                int h = wrz * 16 + (l >> 4) * 4 + j;
                int s = wcz * 48 + ni * 16 + (l & 15);
                *(unsigned short*)(Ztl + h * 192 + (((s >> 3) ^ (h & 3)) << 4) + (s & 7) * 2)
                    = f2bf(zacc[ni][j]);
            }
    };

    stageW(Wl0, 0);
    stageA2(0);
    __syncthreads();                      // Xs, Wl0, A2l(r=0) ready

    char* Wcur = Wl0;
    char* Wnxt = Wl1;
    for (int r = 0; r < Rq; ++r) {
        f32x4 zacc[3];
        gemmZ(Wcur, zacc);                // reads Wcur, Xs
        stageW(Wnxt, r + 1);              // prefetch next slice (r+1; r=4 -> root slice 5)
        writeZt(zacc);                    // Ztl free (prev consumer done at last sync)
        __syncthreads();                  // Ztl visible; A2l loads drained
        // acc[nl][h] += A2_r @ Zt^T : K = 96 s
#pragma unroll
        for (int ks = 0; ks < 3; ++ks) {
            int kb = ks * 64 + (l >> 4) * 16;
            int h = wcn * 16 + (l & 15);
            bf16x8 bfv = *(const bf16x8*)(Ztl + h * 192 + (kb ^ ((h & 3) << 4)));
#pragma unroll
            for (int mi = 0; mi < 3; ++mi) {
                int nl = wrn * 48 + mi * 16 + (l & 15);
                bf16x8 af = *(const bf16x8*)(A2l + nl * 192 + (kb ^ ((nl & 3) << 4)));
                acc[mi] = __builtin_amdgcn_mfma_f32_16x16x32_bf16(af, bfv, acc[mi], 0, 0, 0);
            }
        }
        __syncthreads();                  // out-MFMA done reading A2l & Ztl
        if (r < Rq - 1) stageA2(r + 1);   // refill A2l for next relation
        char* t2 = Wcur; Wcur = Wnxt; Wnxt = t2;
    }

    // root term: Z5 = root-chunk @ X^T (already staged in Wcur), add elementwise
    f32x4 zacc[3];
    gemmZ(Wcur, zacc);
    writeZt(zacc);
    __syncthreads();
#pragma unroll
    for (int mi = 0; mi < 3; ++mi) {
        int h = wcn * 16 + (l & 15);
#pragma unroll
        for (int j = 0; j < 4; ++j) {
            int nl = wrn * 48 + mi * 16 + (l >> 4) * 4 + j;
            float rv = bf2f(*(const unsigned short*)(Ztl + h * 192 +
                            (((nl >> 3) ^ (h & 3)) << 4) + (nl & 7) * 2));
            acc[mi][j] += rv;
        }
    }

    {
        int h = wcn * 16 + (l & 15);
        float bv = bias[hc * 64 + h];
#pragma unroll
        for (int mi = 0; mi < 3; ++mi)
#pragma unroll
            for (int j = 0; j < 4; ++j) {
                int nl = wrn * 48 + mi * 16 + (l >> 4) * 4 + j;
                if (nl < NPGq)
                    out[((size_t)b * NPGq + nl) * Hq + hc * 64 + h] = acc[mi][j] + bv;
            }
    }
}

extern "C" void kernel_launch(void* const* d_in, const int* in_sizes, int n_in,
                              void* d_out, int out_size, void* d_ws, size_t ws_size,
                              hipStream_t stream) {
    (void)in_sizes; (void)n_in; (void)out_size; (void)ws_size;
    const float* M     = (const float*)d_in[0];
    const float* x     = (const float*)d_in[1];
    const float* natt  = (const float*)d_in[2];
    const float* Ws    = (const float*)d_in[3];
    const float* bases = (const float*)d_in[4];
    const float* comp  = (const float*)d_in[5];
    const float* rootw = (const float*)d_in[6];
    const float* bias  = (const float*)d_in[7];
    const int* esrc    = (const int*)d_in[8];
    const int* edst    = (const int*)d_in[9];
    const int* etype   = (const int*)d_in[10];
    float* out = (float*)d_out;
    char* ws = (char*)d_ws;

    unsigned short* Wt  = (unsigned short*)(ws + 0);          //    786,432 B
    unsigned short* A2b = (unsigned short*)(ws + 786432);     //  5,898,240 B
    unsigned short* xb  = (unsigned short*)(ws + 6684672);    //  3,145,728 B (total ~9.8 MB)

    k_pa<<<dim3(454), 576, 0, stream>>>(M, Ws, natt, esrc, edst, etype,
                                        x, bases, comp, rootw, A2b, xb, Wt);
    k_gemm3<<<dim3(4, Bq), 512, 0, stream>>>(A2b, Wt, xb, bias, out);
}